// Round 5
// baseline (110.379 us; speedup 1.0000x reference)
//
#include <hip/hip_runtime.h>
#include <hip/hip_bf16.h>

typedef __attribute__((ext_vector_type(8))) short bf16x8;
typedef __attribute__((ext_vector_type(4))) float f32x4;
typedef __attribute__((ext_vector_type(16))) float f32x16;

#define NB 32
#define NC 256
#define NN 1024

__device__ __forceinline__ unsigned pack2(float a, float b) {
    __hip_bfloat16 ha = __float2bfloat16(a), hb = __float2bfloat16(b);
    unsigned short ua = *(unsigned short*)&ha, ub = *(unsigned short*)&hb;
    return (unsigned)ua | ((unsigned)ub << 16);
}

// async global->LDS, 16B per lane; LDS dest = wave-uniform base + lane*16
__device__ __forceinline__ void glds16(const __hip_bfloat16* g, void* lds) {
    __builtin_amdgcn_global_load_lds(
        (const __attribute__((address_space(1))) unsigned int*)g,
        (__attribute__((address_space(3))) unsigned int*)lds, 16, 0, 0);
}

// ---------------------------------------------------------------------------
// Kernel 0: transpose+cast  x[b][c][n] f32 -> Xt[b][n][c] bf16
// ---------------------------------------------------------------------------
__global__ __launch_bounds__(256) void xpose_kernel(
    const float* __restrict__ x, __hip_bfloat16* __restrict__ Xt)
{
    __shared__ float Ls[64 * 67];
    const int t = threadIdx.x;
    const int n0 = blockIdx.x * 64, c0 = blockIdx.y * 64, b = blockIdx.z;
    const int cl = t >> 4, nl = (t & 15) * 4;
    const float* xb = x + ((size_t)b * NC + c0) * NN + n0;
    #pragma unroll
    for (int q4 = 0; q4 < 4; ++q4) {
        const int c = cl + q4 * 16;
        const float4 v = *(const float4*)(xb + (size_t)c * NN + nl);
        Ls[(nl + 0) * 67 + c] = v.x;
        Ls[(nl + 1) * 67 + c] = v.y;
        Ls[(nl + 2) * 67 + c] = v.z;
        Ls[(nl + 3) * 67 + c] = v.w;
    }
    __syncthreads();
    #pragma unroll
    for (int p = 0; p < 2; ++p) {
        const int idx = p * 256 + t, n = idx >> 3, cs = idx & 7;
        const float* r = &Ls[n * 67 + cs * 8];
        uint4 o;
        o.x = pack2(r[0], r[1]); o.y = pack2(r[2], r[3]);
        o.z = pack2(r[4], r[5]); o.w = pack2(r[6], r[7]);
        *(uint4*)(Xt + ((size_t)b * NN + n0 + n) * NC + c0 + cs * 8) = o;
    }
}

// ---------------------------------------------------------------------------
// Shared GEMM staging (element-traced swizzle; unchanged).
// ---------------------------------------------------------------------------
__device__ __forceinline__ void stage_ab(const __hip_bfloat16* __restrict__ Ag,
                                         const float* __restrict__ Bg,
                                         char* Ad, char* Bd, int ks, int t)
{
    const int srow = t >> 3, spch = t & 7;
    #pragma unroll
    for (int it = 0; it < 4; ++it) {
        const int row = it * 32 + srow;
        const int sw  = row & 7;
        glds16(Ag + (size_t)row * NC + ks * 64 + ((spch ^ sw) << 3),
               Ad + (it * 256 + t) * 16);
        const float* wp = Bg + (size_t)row * NC + ks * 64 + (spch << 3);
        const float4 u0 = *(const float4*)wp;
        const float4 u1 = *(const float4*)(wp + 4);
        uint4 pk;
        pk.x = pack2(u0.x, u0.y); pk.y = pack2(u0.z, u0.w);
        pk.z = pack2(u1.x, u1.y); pk.w = pack2(u1.z, u1.w);
        *(uint4*)(Bd + row * 128 + ((spch ^ sw) << 4)) = pk;
    }
}

// ---------------------------------------------------------------------------
// Kernel 1: QKV projection GEMM (bf16 MFMA) — unchanged.
// ---------------------------------------------------------------------------
__global__ __launch_bounds__(256, 2) void qkv_gemm_kernel(
    const __hip_bfloat16* __restrict__ Xt, const float* __restrict__ w_in,
    const float* __restrict__ b_in, __hip_bfloat16* __restrict__ Qt,
    __hip_bfloat16* __restrict__ Kt, __hip_bfloat16* __restrict__ Vx)
{
    __shared__ char smem[65536];
    char* const A0 = smem;
    char* const A1 = smem + 16384;
    char* const B0 = smem + 32768;
    char* const B1 = smem + 49152;

    const int t  = threadIdx.x;
    const int wv = t >> 6, ln = t & 63, lo = ln & 15, hi = ln >> 4;
    const int wm = wv >> 1, wn = wv & 1;
    const int n0 = blockIdx.x * 128, o0 = blockIdx.y * 128, b = blockIdx.z;

    const __hip_bfloat16* Ag = Xt + ((size_t)b * NN + n0) * NC;
    const float* Bg = w_in + (size_t)o0 * NC;

    f32x4 acc[4][4];
    #pragma unroll
    for (int i = 0; i < 4; ++i)
        #pragma unroll
        for (int j = 0; j < 4; ++j) acc[i][j] = (f32x4){0.f, 0.f, 0.f, 0.f};

    int ra[4], rb[4];
    #pragma unroll
    for (int f = 0; f < 4; ++f) { ra[f] = wm * 64 + f * 16 + lo; rb[f] = wn * 64 + f * 16 + lo; }

    stage_ab(Ag, Bg, A0, B0, 0, t);
    __syncthreads();
    #pragma unroll
    for (int ks = 0; ks < 4; ++ks) {
        char* Ac = (ks & 1) ? A1 : A0;
        char* Bc = (ks & 1) ? B1 : B0;
        if (ks < 3)
            stage_ab(Ag, Bg, (ks & 1) ? A0 : A1, (ks & 1) ? B0 : B1, ks + 1, t);
        #pragma unroll
        for (int kk = 0; kk < 2; ++kk) {
            bf16x8 av[4], bv[4];
            #pragma unroll
            for (int f = 0; f < 4; ++f) {
                av[f] = *(const bf16x8*)(Ac + ra[f] * 128 + (((kk << 2) | hi) ^ (ra[f] & 7)) * 16);
                bv[f] = *(const bf16x8*)(Bc + rb[f] * 128 + (((kk << 2) | hi) ^ (rb[f] & 7)) * 16);
            }
            #pragma unroll
            for (int fm = 0; fm < 4; ++fm)
                #pragma unroll
                for (int fn = 0; fn < 4; ++fn)
                    acc[fm][fn] = __builtin_amdgcn_mfma_f32_16x16x32_bf16(
                        av[fm], bv[fn], acc[fm][fn], 0, 0, 0);
        }
        __syncthreads();
    }

    float bias[4];
    #pragma unroll
    for (int fn = 0; fn < 4; ++fn) bias[fn] = b_in[o0 + wn * 64 + fn * 16 + lo];

    __hip_bfloat16* Ls = (__hip_bfloat16*)smem;  // [128][136] bf16
    if (o0 < 512) {
        #pragma unroll
        for (int fm = 0; fm < 4; ++fm)
            #pragma unroll
            for (int fn = 0; fn < 4; ++fn)
                #pragma unroll
                for (int r = 0; r < 4; ++r)
                    Ls[(wm * 64 + fm * 16 + hi * 4 + r) * 136 + wn * 64 + fn * 16 + lo] =
                        __float2bfloat16(acc[fm][fn][r] + bias[fn]);
        __syncthreads();
        __hip_bfloat16* dst = (o0 < 256) ? Qt : Kt;
        const int oc = (o0 < 256) ? o0 : o0 - 256;
        #pragma unroll
        for (int p = 0; p < 8; ++p) {
            const int idx = p * 256 + t, row = idx >> 4, ch = idx & 15;
            *(uint4*)(dst + ((size_t)b * NN + n0 + row) * NC + oc + ch * 8) =
                *(const uint4*)&Ls[row * 136 + ch * 8];
        }
    } else {
        #pragma unroll
        for (int fm = 0; fm < 4; ++fm)
            #pragma unroll
            for (int fn = 0; fn < 4; ++fn)
                #pragma unroll
                for (int r = 0; r < 4; ++r)
                    Ls[(wn * 64 + fn * 16 + lo) * 136 + wm * 64 + fm * 16 + hi * 4 + r] =
                        __float2bfloat16(acc[fm][fn][r] + bias[fn]);
        __syncthreads();
        #pragma unroll
        for (int p = 0; p < 8; ++p) {
            const int idx = p * 256 + t, row = idx >> 4, ch = idx & 15;
            *(uint4*)(Vx + ((size_t)b * NC + (o0 - 512) + row) * NN + n0 + ch * 8) =
                *(const uint4*)&Ls[row * 136 + ch * 8];
        }
    }
}

// ---------------------------------------------------------------------------
// Kernel 2: flash attention v4 — 32x32x16 MFMA (2x FLOP per LDS byte).
// 4 waves x 32 q-rows, QBLK=128. Swapped QK^T: sf = mfma(K,Q) -> lane
// (l32,h2) holds 32 scores for q-row l32, keys ksub*32 + (reg&3)+8*(reg>>2)
// +4*h2. Softmax fully in-lane + 1 shfl_xor(32). PV: acc = mfma(V, P):
// A=V from LDS, B=P in-register via partner-exchange:
//   B-frag needs keys kstep*16+h2*8+j; key = 32*(kstep>>1) + 8*(2(kstep&1)
//   +h2) + 4a + r, owner lane h2'=a. Words a=own-h2 kept, a=1-h2 from
//   lane^32: every lane sends pu[ksb][sA+(1-h2)][w], receives what it needs.
// Trace (h2=1,kstep=2): needs keys 40..47; words0,1 from (l32,0): partner
//   sends pu[1][sA=0 +1][·] = keys 32+8*1+{0..3} = 40..43 ✓; words2,3 own
//   pu[1][1][·] = 44..47 ✓.
// grid (8,32), 256 thr; LDS 128K: K[2][64][256] | V[2][256][64] swizzled.
// ---------------------------------------------------------------------------
__device__ __forceinline__ void attn_stage(const __hip_bfloat16* __restrict__ Kbase,
                                           const __hip_bfloat16* __restrict__ Vbase,
                                           char* Kd, char* Vd, int m0, int t)
{
    #pragma unroll
    for (int p = 0; p < 8; ++p) {
        const int idx = p * 256 + t;
        const int row = idx >> 5, pc = idx & 31;
        const int sc = (pc & 24) | ((pc ^ row) & 7);
        glds16(Kbase + (size_t)(m0 + row) * NC + sc * 8, Kd + idx * 16);
    }
    #pragma unroll
    for (int p = 0; p < 8; ++p) {
        const int idx = p * 256 + t;
        const int row = idx >> 3, pc = idx & 7;
        const int sc = pc ^ (row & 7);
        glds16(Vbase + (size_t)row * NN + m0 + sc * 8, Vd + idx * 16);
    }
}

__global__ __launch_bounds__(256, 1) void attn_kernel(
    const __hip_bfloat16* __restrict__ Qt, const __hip_bfloat16* __restrict__ Kt,
    const __hip_bfloat16* __restrict__ Vx, __hip_bfloat16* __restrict__ Ht)
{
    __shared__ char smem[131072];   // K dbuf 2x32KB | V dbuf 2x32KB

    const int t  = threadIdx.x;
    const int wv = t >> 6, ln = t & 63;
    const int l32 = ln & 31, h2 = ln >> 5;
    const int wid = blockIdx.x + 8 * blockIdx.y;
    const int swz = (wid & 7) * 32 + (wid >> 3);       // XCD gets 4 batches
    const int qb = swz & 7, b = swz >> 3;
    const int n0 = qb * 128;
    const float scale = 0.0625f;  // 1/sqrt(256)

    const __hip_bfloat16* Kbase = Kt + (size_t)b * NN * NC;
    const __hip_bfloat16* Vbase = Vx + (size_t)b * NC * NN;

    // Q B-frags: q-col = n0 + wv*32 + l32; k chunk = ks*16 + h2*8
    const __hip_bfloat16* qp = Qt + ((size_t)b * NN + n0 + wv * 32 + l32) * NC;
    bf16x8 qf[16];
    #pragma unroll
    for (int ks = 0; ks < 16; ++ks)
        qf[ks] = *(const bf16x8*)(qp + ks * 16 + h2 * 8);

    f32x16 acc[8];
    #pragma unroll
    for (int ct = 0; ct < 8; ++ct)
        #pragma unroll
        for (int r = 0; r < 16; ++r) acc[ct][r] = 0.f;
    float mr = 0.f;   // running max for q-row l32 (defer-max; scores O(1))
    float sr = 0.f;   // running denom

    attn_stage(Kbase, Vbase, smem, smem + 65536, 0, t);
    __syncthreads();   // drains vmcnt -> tile 0 resident

    for (int mc = 0; mc < 16; ++mc) {
        const int cb = mc & 1;
        char* const Kc = smem + cb * 32768;
        char* const Vc = smem + 65536 + cb * 32768;
        if (mc < 15)
            attn_stage(Kbase, Vbase, smem + (cb ^ 1) * 32768,
                       smem + 65536 + (cb ^ 1) * 32768, (mc + 1) * 64, t);

        // S^T = K Q^T : sf[ksub] = 32 keys x 32 q
        f32x16 sf[2];
        #pragma unroll
        for (int ksub = 0; ksub < 2; ++ksub)
            #pragma unroll
            for (int r = 0; r < 16; ++r) sf[ksub][r] = 0.f;
        __builtin_amdgcn_s_setprio(1);
        #pragma unroll
        for (int ksub = 0; ksub < 2; ++ksub) {
            const int row = ksub * 32 + l32;
            #pragma unroll
            for (int ks = 0; ks < 16; ++ks) {
                const int c  = 2 * ks + h2;
                const int pc = (c & 24) | ((c ^ row) & 7);
                bf16x8 kf = *(const bf16x8*)(Kc + row * 512 + pc * 16);
                sf[ksub] = __builtin_amdgcn_mfma_f32_32x32x16_bf16(kf, qf[ks], sf[ksub], 0, 0, 0);
            }
        }
        __builtin_amdgcn_s_setprio(0);

        // softmax for q-row l32: in-lane over 32 + 1 shfl
        float tm = sf[0][0];
        #pragma unroll
        for (int ksub = 0; ksub < 2; ++ksub)
            #pragma unroll
            for (int r = 0; r < 16; ++r) tm = fmaxf(tm, sf[ksub][r]);
        tm = fmaxf(tm, __shfl_xor(tm, 32, 64));
        tm *= scale;
        if (__any(tm > mr + 8.f)) {
            const float mn = fmaxf(mr, tm);
            const float al = __expf(mr - mn);
            mr = mn;
            sr *= al;
            #pragma unroll
            for (int ct = 0; ct < 8; ++ct)
                #pragma unroll
                for (int r = 0; r < 16; ++r) acc[ct][r] *= al;
        }
        float p[2][16];
        float s = 0.f;
        #pragma unroll
        for (int ksub = 0; ksub < 2; ++ksub)
            #pragma unroll
            for (int r = 0; r < 16; ++r) {
                p[ksub][r] = __expf(sf[ksub][r] * scale - mr);
                s += p[ksub][r];
            }
        s += __shfl_xor(s, 32, 64);
        sr += s;

        // pack P and build PV B-frags via one lane^32 exchange per word
        unsigned pu[2][4][2];
        #pragma unroll
        for (int ksub = 0; ksub < 2; ++ksub)
            #pragma unroll
            for (int ss = 0; ss < 4; ++ss) {
                pu[ksub][ss][0] = pack2(p[ksub][ss * 4 + 0], p[ksub][ss * 4 + 1]);
                pu[ksub][ss][1] = pack2(p[ksub][ss * 4 + 2], p[ksub][ss * 4 + 3]);
            }
        bf16x8 pb[4];
        #pragma unroll
        for (int kstep = 0; kstep < 4; ++kstep) {
            const int ksb = kstep >> 1, sA = 2 * (kstep & 1);
            const unsigned own0 = h2 ? pu[ksb][sA + 1][0] : pu[ksb][sA][0];
            const unsigned own1 = h2 ? pu[ksb][sA + 1][1] : pu[ksb][sA][1];
            const unsigned snd0 = h2 ? pu[ksb][sA][0] : pu[ksb][sA + 1][0];
            const unsigned snd1 = h2 ? pu[ksb][sA][1] : pu[ksb][sA + 1][1];
            const unsigned rc0 = (unsigned)__shfl_xor((int)snd0, 32, 64);
            const unsigned rc1 = (unsigned)__shfl_xor((int)snd1, 32, 64);
            union { unsigned u[4]; bf16x8 v; } uu;
            uu.u[0] = h2 ? rc0 : own0;
            uu.u[1] = h2 ? rc1 : own1;
            uu.u[2] = h2 ? own0 : rc0;
            uu.u[3] = h2 ? own1 : rc1;
            pb[kstep] = uu.v;
        }

        // H^T += V^T P : acc[ct] = 32 c x 32 q
        __builtin_amdgcn_s_setprio(1);
        #pragma unroll
        for (int ct = 0; ct < 8; ++ct) {
            const int row = ct * 32 + l32;
            #pragma unroll
            for (int kstep = 0; kstep < 4; ++kstep) {
                const int pc = (2 * kstep + h2) ^ (row & 7);
                bf16x8 vf = *(const bf16x8*)(Vc + row * 128 + pc * 16);
                acc[ct] = __builtin_amdgcn_mfma_f32_32x32x16_bf16(vf, pb[kstep], acc[ct], 0, 0, 0);
            }
        }
        __builtin_amdgcn_s_setprio(0);
        __syncthreads();  // drains vmcnt(0): next tile resident; buffers swappable
    }

    // epilogue: lane (l32,h2) holds q=n0+wv*32+l32, c = ct*32+(r&3)+8*(r>>2)+4*h2
    const float inv = 1.0f / sr;
    __hip_bfloat16* W = (__hip_bfloat16*)(smem + wv * 17408);  // [32][264] bf16
    #pragma unroll
    for (int ct = 0; ct < 8; ++ct)
        #pragma unroll
        for (int ss = 0; ss < 4; ++ss) {
            uint2 v;
            v.x = pack2(acc[ct][ss * 4 + 0] * inv, acc[ct][ss * 4 + 1] * inv);
            v.y = pack2(acc[ct][ss * 4 + 2] * inv, acc[ct][ss * 4 + 3] * inv);
            *(uint2*)&W[l32 * 264 + ct * 32 + ss * 8 + h2 * 4] = v;
        }
    asm volatile("s_waitcnt lgkmcnt(0)" ::: "memory");
    __builtin_amdgcn_sched_barrier(0);
    __hip_bfloat16* hrow0 = Ht + ((size_t)b * NN + n0 + wv * 32) * NC;
    #pragma unroll
    for (int rnd = 0; rnd < 16; ++rnd) {
        const int row = rnd * 2 + h2;
        *(uint4*)(hrow0 + (size_t)row * NC + l32 * 8) = *(const uint4*)&W[row * 264 + l32 * 8];
    }
}

// ---------------------------------------------------------------------------
// Kernel 3: output projection GEMM (bf16 MFMA) + bias + skip — unchanged.
// ---------------------------------------------------------------------------
__global__ __launch_bounds__(256, 2) void out_gemm_kernel(
    const __hip_bfloat16* __restrict__ Ht, const float* __restrict__ w_out,
    const float* __restrict__ b_out, const float* __restrict__ x,
    float* __restrict__ out)
{
    __shared__ char smem[65536];
    char* const A0 = smem;
    char* const A1 = smem + 16384;
    char* const B0 = smem + 32768;
    char* const B1 = smem + 49152;

    const int t  = threadIdx.x;
    const int wv = t >> 6, ln = t & 63, lo = ln & 15, hi = ln >> 4;
    const int wm = wv >> 1, wn = wv & 1;
    const int n0 = blockIdx.x * 128, o0 = blockIdx.y * 128, b = blockIdx.z;

    const float* Ag = w_out + (size_t)o0 * NC;
    const __hip_bfloat16* Bg = Ht + ((size_t)b * NN + n0) * NC;

    f32x4 acc[4][4];
    #pragma unroll
    for (int i = 0; i < 4; ++i)
        #pragma unroll
        for (int j = 0; j < 4; ++j) acc[i][j] = (f32x4){0.f, 0.f, 0.f, 0.f};

    int ra[4], rb[4];
    #pragma unroll
    for (int f = 0; f < 4; ++f) { ra[f] = wm * 64 + f * 16 + lo; rb[f] = wn * 64 + f * 16 + lo; }

    stage_ab(Bg, Ag, B0, A0, 0, t);
    __syncthreads();
    #pragma unroll
    for (int ks = 0; ks < 4; ++ks) {
        char* Ac = (ks & 1) ? A1 : A0;
        char* Bc = (ks & 1) ? B1 : B0;
        if (ks < 3)
            stage_ab(Bg, Ag, (ks & 1) ? B0 : B1, (ks & 1) ? A0 : A1, ks + 1, t);
        #pragma unroll
        for (int kk = 0; kk < 2; ++kk) {
            bf16x8 av[4], bv[4];
            #pragma unroll
            for (int f = 0; f < 4; ++f) {
                av[f] = *(const bf16x8*)(Ac + ra[f] * 128 + (((kk << 2) | hi) ^ (ra[f] & 7)) * 16);
                bv[f] = *(const bf16x8*)(Bc + rb[f] * 128 + (((kk << 2) | hi) ^ (rb[f] & 7)) * 16);
            }
            #pragma unroll
            for (int fm = 0; fm < 4; ++fm)
                #pragma unroll
                for (int fn = 0; fn < 4; ++fn)
                    acc[fm][fn] = __builtin_amdgcn_mfma_f32_16x16x32_bf16(
                        av[fm], bv[fn], acc[fm][fn], 0, 0, 0);
        }
        __syncthreads();
    }

    #pragma unroll
    for (int fm = 0; fm < 4; ++fm) {
        #pragma unroll
        for (int r = 0; r < 4; ++r) {
            const int o = o0 + wm * 64 + fm * 16 + hi * 4 + r;
            const float bo = b_out[o];
            const size_t rowg = ((size_t)b * NC + o) * NN + n0;
            #pragma unroll
            for (int fn = 0; fn < 4; ++fn) {
                const size_t gi = rowg + wn * 64 + fn * 16 + lo;
                out[gi] = acc[fm][fn][r] + bo + x[gi];
            }
        }
    }
}

// ---------------------------------------------------------------------------
extern "C" void kernel_launch(void* const* d_in, const int* in_sizes, int n_in,
                              void* d_out, int out_size, void* d_ws, size_t ws_size,
                              hipStream_t stream) {
    const float* x     = (const float*)d_in[0];
    const float* w_in  = (const float*)d_in[1];
    const float* b_in  = (const float*)d_in[2];
    const float* w_out = (const float*)d_in[3];
    const float* b_out = (const float*)d_in[4];
    float* out = (float*)d_out;

    if (ws_size < (size_t)64 * 1024 * 1024) return;  // fail loud
    char* ws = (char*)d_ws;
    __hip_bfloat16* Qt = (__hip_bfloat16*)(ws);
    __hip_bfloat16* Kt = (__hip_bfloat16*)(ws + ((size_t)16 << 20));
    __hip_bfloat16* Vx = (__hip_bfloat16*)(ws + ((size_t)32 << 20));
    __hip_bfloat16* Xt = (__hip_bfloat16*)(ws + ((size_t)48 << 20));  // aliased as Ht
    __hip_bfloat16* Ht = Xt;  // Xt dead after qkv_gemm

    xpose_kernel<<<dim3(16, 4, 32), 256, 0, stream>>>(x, Xt);
    qkv_gemm_kernel<<<dim3(8, 6, 32), 256, 0, stream>>>(Xt, w_in, b_in, Qt, Kt, Vx);
    attn_kernel<<<dim3(8, 32), 256, 0, stream>>>(Qt, Kt, Vx, Ht);
    out_gemm_kernel<<<dim3(8, 2, 32), 256, 0, stream>>>(Ht, w_out, b_out, x, out);
}

// Round 6
// 108.617 us; speedup vs baseline: 1.0162x; 1.0162x over previous
//
#include <hip/hip_runtime.h>
#include <hip/hip_bf16.h>

typedef __attribute__((ext_vector_type(8))) short bf16x8;
typedef __attribute__((ext_vector_type(4))) float f32x4;
typedef __attribute__((ext_vector_type(16))) float f32x16;

#define NB 32
#define NC 256
#define NN 1024

__device__ __forceinline__ unsigned pack2(float a, float b) {
    __hip_bfloat16 ha = __float2bfloat16(a), hb = __float2bfloat16(b);
    unsigned short ua = *(unsigned short*)&ha, ub = *(unsigned short*)&hb;
    return (unsigned)ua | ((unsigned)ub << 16);
}

// async global->LDS, 16B per lane; LDS dest = wave-uniform base + lane*16
__device__ __forceinline__ void glds16(const __hip_bfloat16* g, void* lds) {
    __builtin_amdgcn_global_load_lds(
        (const __attribute__((address_space(1))) unsigned int*)g,
        (__attribute__((address_space(3))) unsigned int*)lds, 16, 0, 0);
}

// ---------------------------------------------------------------------------
// Kernel 0: transpose+cast  x[b][c][n] f32 -> Xt[b][n][c] bf16
// ---------------------------------------------------------------------------
__global__ __launch_bounds__(256) void xpose_kernel(
    const float* __restrict__ x, __hip_bfloat16* __restrict__ Xt)
{
    __shared__ float Ls[64 * 67];
    const int t = threadIdx.x;
    const int n0 = blockIdx.x * 64, c0 = blockIdx.y * 64, b = blockIdx.z;
    const int cl = t >> 4, nl = (t & 15) * 4;
    const float* xb = x + ((size_t)b * NC + c0) * NN + n0;
    #pragma unroll
    for (int q4 = 0; q4 < 4; ++q4) {
        const int c = cl + q4 * 16;
        const float4 v = *(const float4*)(xb + (size_t)c * NN + nl);
        Ls[(nl + 0) * 67 + c] = v.x;
        Ls[(nl + 1) * 67 + c] = v.y;
        Ls[(nl + 2) * 67 + c] = v.z;
        Ls[(nl + 3) * 67 + c] = v.w;
    }
    __syncthreads();
    #pragma unroll
    for (int p = 0; p < 2; ++p) {
        const int idx = p * 256 + t, n = idx >> 3, cs = idx & 7;
        const float* r = &Ls[n * 67 + cs * 8];
        uint4 o;
        o.x = pack2(r[0], r[1]); o.y = pack2(r[2], r[3]);
        o.z = pack2(r[4], r[5]); o.w = pack2(r[6], r[7]);
        *(uint4*)(Xt + ((size_t)b * NN + n0 + n) * NC + c0 + cs * 8) = o;
    }
}

// ---------------------------------------------------------------------------
// Shared GEMM staging (element-traced swizzle; unchanged).
// ---------------------------------------------------------------------------
__device__ __forceinline__ void stage_ab(const __hip_bfloat16* __restrict__ Ag,
                                         const float* __restrict__ Bg,
                                         char* Ad, char* Bd, int ks, int t)
{
    const int srow = t >> 3, spch = t & 7;
    #pragma unroll
    for (int it = 0; it < 4; ++it) {
        const int row = it * 32 + srow;
        const int sw  = row & 7;
        glds16(Ag + (size_t)row * NC + ks * 64 + ((spch ^ sw) << 3),
               Ad + (it * 256 + t) * 16);
        const float* wp = Bg + (size_t)row * NC + ks * 64 + (spch << 3);
        const float4 u0 = *(const float4*)wp;
        const float4 u1 = *(const float4*)(wp + 4);
        uint4 pk;
        pk.x = pack2(u0.x, u0.y); pk.y = pack2(u0.z, u0.w);
        pk.z = pack2(u1.x, u1.y); pk.w = pack2(u1.z, u1.w);
        *(uint4*)(Bd + row * 128 + ((spch ^ sw) << 4)) = pk;
    }
}

// ---------------------------------------------------------------------------
// Kernel 1: QKV projection GEMM (bf16 MFMA) — unchanged.
// ---------------------------------------------------------------------------
__global__ __launch_bounds__(256, 2) void qkv_gemm_kernel(
    const __hip_bfloat16* __restrict__ Xt, const float* __restrict__ w_in,
    const float* __restrict__ b_in, __hip_bfloat16* __restrict__ Qt,
    __hip_bfloat16* __restrict__ Kt, __hip_bfloat16* __restrict__ Vx)
{
    __shared__ char smem[65536];
    char* const A0 = smem;
    char* const A1 = smem + 16384;
    char* const B0 = smem + 32768;
    char* const B1 = smem + 49152;

    const int t  = threadIdx.x;
    const int wv = t >> 6, ln = t & 63, lo = ln & 15, hi = ln >> 4;
    const int wm = wv >> 1, wn = wv & 1;
    const int n0 = blockIdx.x * 128, o0 = blockIdx.y * 128, b = blockIdx.z;

    const __hip_bfloat16* Ag = Xt + ((size_t)b * NN + n0) * NC;
    const float* Bg = w_in + (size_t)o0 * NC;

    f32x4 acc[4][4];
    #pragma unroll
    for (int i = 0; i < 4; ++i)
        #pragma unroll
        for (int j = 0; j < 4; ++j) acc[i][j] = (f32x4){0.f, 0.f, 0.f, 0.f};

    int ra[4], rb[4];
    #pragma unroll
    for (int f = 0; f < 4; ++f) { ra[f] = wm * 64 + f * 16 + lo; rb[f] = wn * 64 + f * 16 + lo; }

    stage_ab(Ag, Bg, A0, B0, 0, t);
    __syncthreads();
    #pragma unroll
    for (int ks = 0; ks < 4; ++ks) {
        char* Ac = (ks & 1) ? A1 : A0;
        char* Bc = (ks & 1) ? B1 : B0;
        if (ks < 3)
            stage_ab(Ag, Bg, (ks & 1) ? A0 : A1, (ks & 1) ? B0 : B1, ks + 1, t);
        #pragma unroll
        for (int kk = 0; kk < 2; ++kk) {
            bf16x8 av[4], bv[4];
            #pragma unroll
            for (int f = 0; f < 4; ++f) {
                av[f] = *(const bf16x8*)(Ac + ra[f] * 128 + (((kk << 2) | hi) ^ (ra[f] & 7)) * 16);
                bv[f] = *(const bf16x8*)(Bc + rb[f] * 128 + (((kk << 2) | hi) ^ (rb[f] & 7)) * 16);
            }
            #pragma unroll
            for (int fm = 0; fm < 4; ++fm)
                #pragma unroll
                for (int fn = 0; fn < 4; ++fn)
                    acc[fm][fn] = __builtin_amdgcn_mfma_f32_16x16x32_bf16(
                        av[fm], bv[fn], acc[fm][fn], 0, 0, 0);
        }
        __syncthreads();
    }

    float bias[4];
    #pragma unroll
    for (int fn = 0; fn < 4; ++fn) bias[fn] = b_in[o0 + wn * 64 + fn * 16 + lo];

    __hip_bfloat16* Ls = (__hip_bfloat16*)smem;  // [128][136] bf16
    if (o0 < 512) {
        #pragma unroll
        for (int fm = 0; fm < 4; ++fm)
            #pragma unroll
            for (int fn = 0; fn < 4; ++fn)
                #pragma unroll
                for (int r = 0; r < 4; ++r)
                    Ls[(wm * 64 + fm * 16 + hi * 4 + r) * 136 + wn * 64 + fn * 16 + lo] =
                        __float2bfloat16(acc[fm][fn][r] + bias[fn]);
        __syncthreads();
        __hip_bfloat16* dst = (o0 < 256) ? Qt : Kt;
        const int oc = (o0 < 256) ? o0 : o0 - 256;
        #pragma unroll
        for (int p = 0; p < 8; ++p) {
            const int idx = p * 256 + t, row = idx >> 4, ch = idx & 15;
            *(uint4*)(dst + ((size_t)b * NN + n0 + row) * NC + oc + ch * 8) =
                *(const uint4*)&Ls[row * 136 + ch * 8];
        }
    } else {
        #pragma unroll
        for (int fm = 0; fm < 4; ++fm)
            #pragma unroll
            for (int fn = 0; fn < 4; ++fn)
                #pragma unroll
                for (int r = 0; r < 4; ++r)
                    Ls[(wn * 64 + fn * 16 + lo) * 136 + wm * 64 + fm * 16 + hi * 4 + r] =
                        __float2bfloat16(acc[fm][fn][r] + bias[fn]);
        __syncthreads();
        #pragma unroll
        for (int p = 0; p < 8; ++p) {
            const int idx = p * 256 + t, row = idx >> 4, ch = idx & 15;
            *(uint4*)(Vx + ((size_t)b * NC + (o0 - 512) + row) * NN + n0 + ch * 8) =
                *(const uint4*)&Ls[row * 136 + ch * 8];
        }
    }
}

// ---------------------------------------------------------------------------
// Kernel 2: flash attention v5 — 8 waves, k-split pairs, 32x32x16 MFMA.
// Wave (qgrp, half): q-rows n0+qgrp*32.., tiles t≡half (mod 2), KVBLK=32.
// 4 KV slots (slot = tile&3), per step s: compute tiles 2s/2s+1, prefetch
// 2s+2/2s+3 via glds; one barrier/step. Pair-merge (flash k-split) at end.
// K slot [32 keys][32 ch]: sc=(pc&24)|((pc^row)&7)   (trace: c9,r5 -> ok)
// V slot [64 j][16 ch]: row j = c-group 4j..4j+3, u=((c&3)<<2)|c2,
//   phys = u^(j&7)  (trace: c5,c2=2 -> j1,u6,phys7; stage idx23 fetches
//   u=7^1=6 -> c=5,c2=2 ✓)
// P->PV B-frag: lane(l32,h2) kstep: own pu[2k+h2], recv partner pu[2k+1-h2]
//   via shfl_xor(32)  (verified: h2=0 u[0:1]=keys 16k+0..3, u[2:3]=16k+4..7
//   from partner's 4*h2own offset ✓)
// ---------------------------------------------------------------------------
__device__ __forceinline__ void stage_tile(const __hip_bfloat16* __restrict__ Kbase,
                                           const __hip_bfloat16* __restrict__ Vbase,
                                           char* Kd, char* Vd, int m0, int t)
{
    #pragma unroll
    for (int p = 0; p < 2; ++p) {
        const int idx = p * 512 + t;               // 0..1023
        const int row = idx >> 5, pc = idx & 31;
        const int sc = (pc & 24) | ((pc ^ row) & 7);
        glds16(Kbase + (size_t)(m0 + row) * NC + sc * 8, Kd + idx * 16);
    }
    #pragma unroll
    for (int p = 0; p < 2; ++p) {
        const int idx = p * 512 + t;
        const int j = idx >> 4, up = idx & 15;
        const int u = up ^ (j & 7);
        const int c = 4 * j + (u >> 2), c2 = u & 3;
        glds16(Vbase + (size_t)c * NN + m0 + c2 * 8, Vd + idx * 16);
    }
}

__global__ __launch_bounds__(512, 2) void attn_kernel(
    const __hip_bfloat16* __restrict__ Qt, const __hip_bfloat16* __restrict__ Kt,
    const __hip_bfloat16* __restrict__ Vx, __hip_bfloat16* __restrict__ Ht)
{
    __shared__ char smem[139264];   // loop: K 4x16K | V 4x16K; epilogue: 256x136 f32

    const int t  = threadIdx.x;
    const int wv = t >> 6, ln = t & 63;
    const int l32 = ln & 31, h2 = ln >> 5;
    const int qgrp = wv & 3, half = wv >> 2;
    const int wid = blockIdx.x + 8 * blockIdx.y;
    const int swz = (wid & 7) * 32 + (wid >> 3);       // XCD gets 4 batches
    const int qb = swz & 7, b = swz >> 3;
    const int n0 = qb * 128;
    const float scale = 0.0625f;  // 1/sqrt(256)

    const __hip_bfloat16* Kbase = Kt + (size_t)b * NN * NC;
    const __hip_bfloat16* Vbase = Vx + (size_t)b * NC * NN;

    // Q B-frags: q-col = n0 + qgrp*32 + l32; chunk ks*16 + h2*8
    const __hip_bfloat16* qp = Qt + ((size_t)b * NN + n0 + qgrp * 32 + l32) * NC;
    bf16x8 qf[16];
    #pragma unroll
    for (int ks = 0; ks < 16; ++ks)
        qf[ks] = *(const bf16x8*)(qp + ks * 16 + h2 * 8);

    f32x16 acc[8];
    #pragma unroll
    for (int ct = 0; ct < 8; ++ct)
        #pragma unroll
        for (int r = 0; r < 16; ++r) acc[ct][r] = 0.f;
    float mr = 0.f;   // per-q running max (scaled units; defer-max)
    float sr = 0.f;   // per-q running denom

    #pragma unroll
    for (int tt = 0; tt < 4; ++tt)
        stage_tile(Kbase, Vbase, smem + tt * 16384, smem + 65536 + tt * 16384,
                   tt * 32, t);
    __syncthreads();   // drains vmcnt -> tiles 0..3 resident

    for (int s = 0; s < 16; ++s) {
        if (s < 15) {
            const int t2 = 2 * s + 2, t3 = 2 * s + 3;
            stage_tile(Kbase, Vbase, smem + (t2 & 3) * 16384,
                       smem + 65536 + (t2 & 3) * 16384, t2 * 32, t);
            stage_tile(Kbase, Vbase, smem + (t3 & 3) * 16384,
                       smem + 65536 + (t3 & 3) * 16384, t3 * 32, t);
        }
        const int tile = 2 * s + half;
        char* const Kc = smem + (tile & 3) * 16384;
        char* const Vc = smem + 65536 + (tile & 3) * 16384;

        // S^T = K Q^T : lane(l32,h2) -> q=l32, keys (r&3)+8*(r>>2)+4*h2
        f32x16 sf;
        #pragma unroll
        for (int r = 0; r < 16; ++r) sf[r] = 0.f;
        __builtin_amdgcn_s_setprio(1);
        #pragma unroll
        for (int ks = 0; ks < 16; ++ks) {
            const int c  = 2 * ks + h2;
            const int pc = (c & 24) | ((c ^ l32) & 7);
            bf16x8 kf = *(const bf16x8*)(Kc + l32 * 512 + pc * 16);
            sf = __builtin_amdgcn_mfma_f32_32x32x16_bf16(kf, qf[ks], sf, 0, 0, 0);
        }
        __builtin_amdgcn_s_setprio(0);

        // softmax for q-row l32: in-lane over 16 + 1 shfl
        float tm = sf[0];
        #pragma unroll
        for (int r = 1; r < 16; ++r) tm = fmaxf(tm, sf[r]);
        tm = fmaxf(tm, __shfl_xor(tm, 32, 64));
        tm *= scale;
        if (__any(tm > mr + 8.f)) {
            const float mn = fmaxf(mr, tm);
            const float al = __expf(mr - mn);
            mr = mn;
            sr *= al;
            #pragma unroll
            for (int ct = 0; ct < 8; ++ct)
                #pragma unroll
                for (int r = 0; r < 16; ++r) acc[ct][r] *= al;
        }
        float p[16];
        float sacc = 0.f;
        #pragma unroll
        for (int r = 0; r < 16; ++r) {
            p[r] = __expf(sf[r] * scale - mr);
            sacc += p[r];
        }
        sacc += __shfl_xor(sacc, 32, 64);
        sr += sacc;

        // pack P; build PV B-frags with one lane^32 exchange per kstep
        unsigned pu[4][2];
        #pragma unroll
        for (int ss = 0; ss < 4; ++ss) {
            pu[ss][0] = pack2(p[ss * 4 + 0], p[ss * 4 + 1]);
            pu[ss][1] = pack2(p[ss * 4 + 2], p[ss * 4 + 3]);
        }
        bf16x8 pb[2];
        #pragma unroll
        for (int kstep = 0; kstep < 2; ++kstep) {
            const int sown = 2 * kstep + h2, ssnd = 2 * kstep + 1 - h2;
            const unsigned own0 = pu[sown][0], own1 = pu[sown][1];
            const unsigned rc0 = (unsigned)__shfl_xor((int)pu[ssnd][0], 32, 64);
            const unsigned rc1 = (unsigned)__shfl_xor((int)pu[ssnd][1], 32, 64);
            union { unsigned u[4]; bf16x8 v; } uu;
            uu.u[0] = h2 ? rc0 : own0;
            uu.u[1] = h2 ? rc1 : own1;
            uu.u[2] = h2 ? own0 : rc0;
            uu.u[3] = h2 ? own1 : rc1;
            pb[kstep] = uu.v;
        }

        // H^T += V^T P
        __builtin_amdgcn_s_setprio(1);
        #pragma unroll
        for (int ct = 0; ct < 8; ++ct) {
            const int j = ct * 8 + (l32 >> 2);
            #pragma unroll
            for (int kstep = 0; kstep < 2; ++kstep) {
                const int u = ((l32 & 3) << 2) | (2 * kstep + h2);
                const int phys = u ^ (j & 7);
                bf16x8 vf = *(const bf16x8*)(Vc + j * 256 + phys * 16);
                acc[ct] = __builtin_amdgcn_mfma_f32_32x32x16_bf16(vf, pb[kstep], acc[ct], 0, 0, 0);
            }
        }
        __builtin_amdgcn_s_setprio(0);
        __syncthreads();  // drains vmcnt: tiles 2s+2,2s+3 resident; slots reusable
    }

    // pair merge: upper (half=1) dumps partials to LDS; lower merges + stores
    float* const ex = (float*)smem;
    const int slot = (qgrp * 64 + ln) * 136;
    if (half) {
        float* dst = ex + slot;
        #pragma unroll
        for (int ct = 0; ct < 8; ++ct)
            #pragma unroll
            for (int rr = 0; rr < 4; ++rr) {
                f32x4 v = {acc[ct][rr * 4 + 0], acc[ct][rr * 4 + 1],
                           acc[ct][rr * 4 + 2], acc[ct][rr * 4 + 3]};
                *(f32x4*)(dst + ct * 16 + rr * 4) = v;
            }
        dst[128] = mr;
        dst[129] = sr;
    }
    __syncthreads();
    if (!half) {
        const float* src = ex + slot;
        const float mb = src[128], lb = src[129];
        const float m = fmaxf(mr, mb);
        float fa = __expf(mr - m), fb = __expf(mb - m);
        const float inv = 1.0f / (sr * fa + lb * fb);
        fa *= inv; fb *= inv;
        __hip_bfloat16* hp = Ht + ((size_t)b * NN + n0 + qgrp * 32 + l32) * NC;
        #pragma unroll
        for (int ct = 0; ct < 8; ++ct)
            #pragma unroll
            for (int ss = 0; ss < 4; ++ss) {
                const float o0 = acc[ct][ss * 4 + 0] * fa + src[ct * 16 + ss * 4 + 0] * fb;
                const float o1 = acc[ct][ss * 4 + 1] * fa + src[ct * 16 + ss * 4 + 1] * fb;
                const float o2 = acc[ct][ss * 4 + 2] * fa + src[ct * 16 + ss * 4 + 2] * fb;
                const float o3 = acc[ct][ss * 4 + 3] * fa + src[ct * 16 + ss * 4 + 3] * fb;
                uint2 v;
                v.x = pack2(o0, o1);
                v.y = pack2(o2, o3);
                *(uint2*)(hp + ct * 32 + ss * 8 + h2 * 4) = v;
            }
    }
}

// ---------------------------------------------------------------------------
// Kernel 3: output projection GEMM (bf16 MFMA) + bias + skip — unchanged.
// ---------------------------------------------------------------------------
__global__ __launch_bounds__(256, 2) void out_gemm_kernel(
    const __hip_bfloat16* __restrict__ Ht, const float* __restrict__ w_out,
    const float* __restrict__ b_out, const float* __restrict__ x,
    float* __restrict__ out)
{
    __shared__ char smem[65536];
    char* const A0 = smem;
    char* const A1 = smem + 16384;
    char* const B0 = smem + 32768;
    char* const B1 = smem + 49152;

    const int t  = threadIdx.x;
    const int wv = t >> 6, ln = t & 63, lo = ln & 15, hi = ln >> 4;
    const int wm = wv >> 1, wn = wv & 1;
    const int n0 = blockIdx.x * 128, o0 = blockIdx.y * 128, b = blockIdx.z;

    const float* Ag = w_out + (size_t)o0 * NC;
    const __hip_bfloat16* Bg = Ht + ((size_t)b * NN + n0) * NC;

    f32x4 acc[4][4];
    #pragma unroll
    for (int i = 0; i < 4; ++i)
        #pragma unroll
        for (int j = 0; j < 4; ++j) acc[i][j] = (f32x4){0.f, 0.f, 0.f, 0.f};

    int ra[4], rb[4];
    #pragma unroll
    for (int f = 0; f < 4; ++f) { ra[f] = wm * 64 + f * 16 + lo; rb[f] = wn * 64 + f * 16 + lo; }

    stage_ab(Bg, Ag, B0, A0, 0, t);
    __syncthreads();
    #pragma unroll
    for (int ks = 0; ks < 4; ++ks) {
        char* Ac = (ks & 1) ? A1 : A0;
        char* Bc = (ks & 1) ? B1 : B0;
        if (ks < 3)
            stage_ab(Bg, Ag, (ks & 1) ? B0 : B1, (ks & 1) ? A0 : A1, ks + 1, t);
        #pragma unroll
        for (int kk = 0; kk < 2; ++kk) {
            bf16x8 av[4], bv[4];
            #pragma unroll
            for (int f = 0; f < 4; ++f) {
                av[f] = *(const bf16x8*)(Ac + ra[f] * 128 + (((kk << 2) | hi) ^ (ra[f] & 7)) * 16);
                bv[f] = *(const bf16x8*)(Bc + rb[f] * 128 + (((kk << 2) | hi) ^ (rb[f] & 7)) * 16);
            }
            #pragma unroll
            for (int fm = 0; fm < 4; ++fm)
                #pragma unroll
                for (int fn = 0; fn < 4; ++fn)
                    acc[fm][fn] = __builtin_amdgcn_mfma_f32_16x16x32_bf16(
                        av[fm], bv[fn], acc[fm][fn], 0, 0, 0);
        }
        __syncthreads();
    }

    #pragma unroll
    for (int fm = 0; fm < 4; ++fm) {
        #pragma unroll
        for (int r = 0; r < 4; ++r) {
            const int o = o0 + wm * 64 + fm * 16 + hi * 4 + r;
            const float bo = b_out[o];
            const size_t rowg = ((size_t)b * NC + o) * NN + n0;
            #pragma unroll
            for (int fn = 0; fn < 4; ++fn) {
                const size_t gi = rowg + wn * 64 + fn * 16 + lo;
                out[gi] = acc[fm][fn][r] + bo + x[gi];
            }
        }
    }
}

// ---------------------------------------------------------------------------
extern "C" void kernel_launch(void* const* d_in, const int* in_sizes, int n_in,
                              void* d_out, int out_size, void* d_ws, size_t ws_size,
                              hipStream_t stream) {
    const float* x     = (const float*)d_in[0];
    const float* w_in  = (const float*)d_in[1];
    const float* b_in  = (const float*)d_in[2];
    const float* w_out = (const float*)d_in[3];
    const float* b_out = (const float*)d_in[4];
    float* out = (float*)d_out;

    if (ws_size < (size_t)64 * 1024 * 1024) return;  // fail loud
    char* ws = (char*)d_ws;
    __hip_bfloat16* Qt = (__hip_bfloat16*)(ws);
    __hip_bfloat16* Kt = (__hip_bfloat16*)(ws + ((size_t)16 << 20));
    __hip_bfloat16* Vx = (__hip_bfloat16*)(ws + ((size_t)32 << 20));
    __hip_bfloat16* Xt = (__hip_bfloat16*)(ws + ((size_t)48 << 20));  // aliased as Ht
    __hip_bfloat16* Ht = Xt;  // Xt dead after qkv_gemm

    xpose_kernel<<<dim3(16, 4, 32), 256, 0, stream>>>(x, Xt);
    qkv_gemm_kernel<<<dim3(8, 6, 32), 256, 0, stream>>>(Xt, w_in, b_in, Qt, Kt, Vx);
    attn_kernel<<<dim3(8, 32), 512, 0, stream>>>(Qt, Kt, Vx, Ht);
    out_gemm_kernel<<<dim3(8, 2, 32), 256, 0, stream>>>(Ht, w_out, b_out, x, out);
}

// Round 7
// 108.160 us; speedup vs baseline: 1.0205x; 1.0042x over previous
//
#include <hip/hip_runtime.h>
#include <hip/hip_bf16.h>

typedef __attribute__((ext_vector_type(8))) short bf16x8;
typedef __attribute__((ext_vector_type(4))) float f32x4;
typedef __attribute__((ext_vector_type(16))) float f32x16;

#define NB 32
#define NC 256
#define NN 1024

__device__ __forceinline__ unsigned pack2(float a, float b) {
    __hip_bfloat16 ha = __float2bfloat16(a), hb = __float2bfloat16(b);
    unsigned short ua = *(unsigned short*)&ha, ub = *(unsigned short*)&hb;
    return (unsigned)ua | ((unsigned)ub << 16);
}

// async global->LDS, 16B per lane; LDS dest = wave-uniform base + lane*16
__device__ __forceinline__ void glds16(const __hip_bfloat16* g, void* lds) {
    __builtin_amdgcn_global_load_lds(
        (const __attribute__((address_space(1))) unsigned int*)g,
        (__attribute__((address_space(3))) unsigned int*)lds, 16, 0, 0);
}

// ---------------------------------------------------------------------------
// Kernel 0: transpose+cast  x[b][c][n] f32 -> Xt[b][n][c] bf16
// ---------------------------------------------------------------------------
__global__ __launch_bounds__(256) void xpose_kernel(
    const float* __restrict__ x, __hip_bfloat16* __restrict__ Xt)
{
    __shared__ float Ls[64 * 67];
    const int t = threadIdx.x;
    const int n0 = blockIdx.x * 64, c0 = blockIdx.y * 64, b = blockIdx.z;
    const int cl = t >> 4, nl = (t & 15) * 4;
    const float* xb = x + ((size_t)b * NC + c0) * NN + n0;
    #pragma unroll
    for (int q4 = 0; q4 < 4; ++q4) {
        const int c = cl + q4 * 16;
        const float4 v = *(const float4*)(xb + (size_t)c * NN + nl);
        Ls[(nl + 0) * 67 + c] = v.x;
        Ls[(nl + 1) * 67 + c] = v.y;
        Ls[(nl + 2) * 67 + c] = v.z;
        Ls[(nl + 3) * 67 + c] = v.w;
    }
    __syncthreads();
    #pragma unroll
    for (int p = 0; p < 2; ++p) {
        const int idx = p * 256 + t, n = idx >> 3, cs = idx & 7;
        const float* r = &Ls[n * 67 + cs * 8];
        uint4 o;
        o.x = pack2(r[0], r[1]); o.y = pack2(r[2], r[3]);
        o.z = pack2(r[4], r[5]); o.w = pack2(r[6], r[7]);
        *(uint4*)(Xt + ((size_t)b * NN + n0 + n) * NC + c0 + cs * 8) = o;
    }
}

// ---------------------------------------------------------------------------
// Shared GEMM staging (element-traced swizzle; unchanged).
// ---------------------------------------------------------------------------
__device__ __forceinline__ void stage_ab(const __hip_bfloat16* __restrict__ Ag,
                                         const float* __restrict__ Bg,
                                         char* Ad, char* Bd, int ks, int t)
{
    const int srow = t >> 3, spch = t & 7;
    #pragma unroll
    for (int it = 0; it < 4; ++it) {
        const int row = it * 32 + srow;
        const int sw  = row & 7;
        glds16(Ag + (size_t)row * NC + ks * 64 + ((spch ^ sw) << 3),
               Ad + (it * 256 + t) * 16);
        const float* wp = Bg + (size_t)row * NC + ks * 64 + (spch << 3);
        const float4 u0 = *(const float4*)wp;
        const float4 u1 = *(const float4*)(wp + 4);
        uint4 pk;
        pk.x = pack2(u0.x, u0.y); pk.y = pack2(u0.z, u0.w);
        pk.z = pack2(u1.x, u1.y); pk.w = pack2(u1.z, u1.w);
        *(uint4*)(Bd + row * 128 + ((spch ^ sw) << 4)) = pk;
    }
}

// ---------------------------------------------------------------------------
// Kernel 1: QKV projection GEMM (bf16 MFMA) — unchanged.
// ---------------------------------------------------------------------------
__global__ __launch_bounds__(256, 2) void qkv_gemm_kernel(
    const __hip_bfloat16* __restrict__ Xt, const float* __restrict__ w_in,
    const float* __restrict__ b_in, __hip_bfloat16* __restrict__ Qt,
    __hip_bfloat16* __restrict__ Kt, __hip_bfloat16* __restrict__ Vx)
{
    __shared__ char smem[65536];
    char* const A0 = smem;
    char* const A1 = smem + 16384;
    char* const B0 = smem + 32768;
    char* const B1 = smem + 49152;

    const int t  = threadIdx.x;
    const int wv = t >> 6, ln = t & 63, lo = ln & 15, hi = ln >> 4;
    const int wm = wv >> 1, wn = wv & 1;
    const int n0 = blockIdx.x * 128, o0 = blockIdx.y * 128, b = blockIdx.z;

    const __hip_bfloat16* Ag = Xt + ((size_t)b * NN + n0) * NC;
    const float* Bg = w_in + (size_t)o0 * NC;

    f32x4 acc[4][4];
    #pragma unroll
    for (int i = 0; i < 4; ++i)
        #pragma unroll
        for (int j = 0; j < 4; ++j) acc[i][j] = (f32x4){0.f, 0.f, 0.f, 0.f};

    int ra[4], rb[4];
    #pragma unroll
    for (int f = 0; f < 4; ++f) { ra[f] = wm * 64 + f * 16 + lo; rb[f] = wn * 64 + f * 16 + lo; }

    stage_ab(Ag, Bg, A0, B0, 0, t);
    __syncthreads();
    #pragma unroll
    for (int ks = 0; ks < 4; ++ks) {
        char* Ac = (ks & 1) ? A1 : A0;
        char* Bc = (ks & 1) ? B1 : B0;
        if (ks < 3)
            stage_ab(Ag, Bg, (ks & 1) ? A0 : A1, (ks & 1) ? B0 : B1, ks + 1, t);
        #pragma unroll
        for (int kk = 0; kk < 2; ++kk) {
            bf16x8 av[4], bv[4];
            #pragma unroll
            for (int f = 0; f < 4; ++f) {
                av[f] = *(const bf16x8*)(Ac + ra[f] * 128 + (((kk << 2) | hi) ^ (ra[f] & 7)) * 16);
                bv[f] = *(const bf16x8*)(Bc + rb[f] * 128 + (((kk << 2) | hi) ^ (rb[f] & 7)) * 16);
            }
            #pragma unroll
            for (int fm = 0; fm < 4; ++fm)
                #pragma unroll
                for (int fn = 0; fn < 4; ++fn)
                    acc[fm][fn] = __builtin_amdgcn_mfma_f32_16x16x32_bf16(
                        av[fm], bv[fn], acc[fm][fn], 0, 0, 0);
        }
        __syncthreads();
    }

    float bias[4];
    #pragma unroll
    for (int fn = 0; fn < 4; ++fn) bias[fn] = b_in[o0 + wn * 64 + fn * 16 + lo];

    __hip_bfloat16* Ls = (__hip_bfloat16*)smem;  // [128][136] bf16
    if (o0 < 512) {
        #pragma unroll
        for (int fm = 0; fm < 4; ++fm)
            #pragma unroll
            for (int fn = 0; fn < 4; ++fn)
                #pragma unroll
                for (int r = 0; r < 4; ++r)
                    Ls[(wm * 64 + fm * 16 + hi * 4 + r) * 136 + wn * 64 + fn * 16 + lo] =
                        __float2bfloat16(acc[fm][fn][r] + bias[fn]);
        __syncthreads();
        __hip_bfloat16* dst = (o0 < 256) ? Qt : Kt;
        const int oc = (o0 < 256) ? o0 : o0 - 256;
        #pragma unroll
        for (int p = 0; p < 8; ++p) {
            const int idx = p * 256 + t, row = idx >> 4, ch = idx & 15;
            *(uint4*)(dst + ((size_t)b * NN + n0 + row) * NC + oc + ch * 8) =
                *(const uint4*)&Ls[row * 136 + ch * 8];
        }
    } else {
        #pragma unroll
        for (int fm = 0; fm < 4; ++fm)
            #pragma unroll
            for (int fn = 0; fn < 4; ++fn)
                #pragma unroll
                for (int r = 0; r < 4; ++r)
                    Ls[(wn * 64 + fn * 16 + lo) * 136 + wm * 64 + fm * 16 + hi * 4 + r] =
                        __float2bfloat16(acc[fm][fn][r] + bias[fn]);
        __syncthreads();
        #pragma unroll
        for (int p = 0; p < 8; ++p) {
            const int idx = p * 256 + t, row = idx >> 4, ch = idx & 15;
            *(uint4*)(Vx + ((size_t)b * NC + (o0 - 512) + row) * NN + n0 + ch * 8) =
                *(const uint4*)&Ls[row * 136 + ch * 8];
        }
    }
}

// ---------------------------------------------------------------------------
// Kernel 2: flash attention v6 — zero-shuffle PV via K-row permutation.
// Structure as v5 (8 waves = 4 qgrp x 2 half, KVBLK=32, 4 slots, pair-merge).
// K LDS rows permuted by pi = swap bits 2<->3 of the 5-bit row index:
//   phys row rho holds global key m0 + pi(rho). QK D-row rho = score(pi(rho)).
//   Lane p[r] = score(pi((r&3)+8*(r>>2)+4*h2)). PV B-frag element (kstep,j)
//   needs score at phys V position 16*kstep+8*h2+j. With r = j+8*kstep:
//   rho(r) = (j&3)+8*(j>>2)+16*kstep+4*h2 (bits: b2=h2, b3=j>>2, b4=kstep)
//   pi(rho) = (j&3)+4*(j>>2)+8*h2+16*kstep = 16*kstep+8*h2+j.  EXACT match
//   -> pb[kstep] = pack(p[8*kstep..8*kstep+7]), no cross-lane ops.
// Softmax max/sum invariant under key permutation. V layout unchanged.
// Also: QK split into two 8-deep MFMA chains; tree reductions.
// ---------------------------------------------------------------------------
__device__ __forceinline__ void stage_tile(const __hip_bfloat16* __restrict__ Kbase,
                                           const __hip_bfloat16* __restrict__ Vbase,
                                           char* Kd, char* Vd, int m0, int t)
{
    #pragma unroll
    for (int p = 0; p < 2; ++p) {
        const int idx = p * 512 + t;               // 0..1023
        const int row = idx >> 5, pc = idx & 31;
        const int prow = (row & 19) | ((row & 4) << 1) | ((row & 8) >> 1); // pi
        const int sc = (pc & 24) | ((pc ^ row) & 7);
        glds16(Kbase + (size_t)(m0 + prow) * NC + sc * 8, Kd + idx * 16);
    }
    #pragma unroll
    for (int p = 0; p < 2; ++p) {
        const int idx = p * 512 + t;
        const int j = idx >> 4, up = idx & 15;
        const int u = up ^ (j & 7);
        const int c = 4 * j + (u >> 2), c2 = u & 3;
        glds16(Vbase + (size_t)c * NN + m0 + c2 * 8, Vd + idx * 16);
    }
}

__global__ __launch_bounds__(512, 2) void attn_kernel(
    const __hip_bfloat16* __restrict__ Qt, const __hip_bfloat16* __restrict__ Kt,
    const __hip_bfloat16* __restrict__ Vx, __hip_bfloat16* __restrict__ Ht)
{
    __shared__ char smem[139264];   // loop: K 4x16K | V 4x16K; epilogue exchange

    const int t  = threadIdx.x;
    const int wv = t >> 6, ln = t & 63;
    const int l32 = ln & 31, h2 = ln >> 5;
    const int qgrp = wv & 3, half = wv >> 2;
    const int wid = blockIdx.x + 8 * blockIdx.y;
    const int swz = (wid & 7) * 32 + (wid >> 3);       // XCD gets 4 batches
    const int qb = swz & 7, b = swz >> 3;
    const int n0 = qb * 128;
    const float scale = 0.0625f;  // 1/sqrt(256)

    const __hip_bfloat16* Kbase = Kt + (size_t)b * NN * NC;
    const __hip_bfloat16* Vbase = Vx + (size_t)b * NC * NN;

    // Q B-frags: q-col = n0 + qgrp*32 + l32; chunk ks*16 + h2*8
    const __hip_bfloat16* qp = Qt + ((size_t)b * NN + n0 + qgrp * 32 + l32) * NC;
    bf16x8 qf[16];
    #pragma unroll
    for (int ks = 0; ks < 16; ++ks)
        qf[ks] = *(const bf16x8*)(qp + ks * 16 + h2 * 8);

    f32x16 acc[8];
    #pragma unroll
    for (int ct = 0; ct < 8; ++ct)
        #pragma unroll
        for (int r = 0; r < 16; ++r) acc[ct][r] = 0.f;
    float mr = 0.f;   // per-q running max (scaled units; defer-max)
    float sr = 0.f;   // per-q running denom

    #pragma unroll
    for (int tt = 0; tt < 4; ++tt)
        stage_tile(Kbase, Vbase, smem + tt * 16384, smem + 65536 + tt * 16384,
                   tt * 32, t);
    __syncthreads();   // drains vmcnt -> tiles 0..3 resident

    for (int s = 0; s < 16; ++s) {
        if (s < 15) {
            const int t2 = 2 * s + 2, t3 = 2 * s + 3;
            stage_tile(Kbase, Vbase, smem + (t2 & 3) * 16384,
                       smem + 65536 + (t2 & 3) * 16384, t2 * 32, t);
            stage_tile(Kbase, Vbase, smem + (t3 & 3) * 16384,
                       smem + 65536 + (t3 & 3) * 16384, t3 * 32, t);
        }
        const int tile = 2 * s + half;
        char* const Kc = smem + (tile & 3) * 16384;
        char* const Vc = smem + 65536 + (tile & 3) * 16384;

        // S^T = K Q^T : two independent 8-deep chains
        f32x16 sfA, sfB;
        #pragma unroll
        for (int r = 0; r < 16; ++r) { sfA[r] = 0.f; sfB[r] = 0.f; }
        __builtin_amdgcn_s_setprio(1);
        #pragma unroll
        for (int ks = 0; ks < 8; ++ks) {
            const int c  = 2 * ks + h2;
            const int pc = (c & 24) | ((c ^ l32) & 7);
            bf16x8 kf = *(const bf16x8*)(Kc + l32 * 512 + pc * 16);
            sfA = __builtin_amdgcn_mfma_f32_32x32x16_bf16(kf, qf[ks], sfA, 0, 0, 0);
        }
        #pragma unroll
        for (int ks = 8; ks < 16; ++ks) {
            const int c  = 2 * ks + h2;
            const int pc = (c & 24) | ((c ^ l32) & 7);
            bf16x8 kf = *(const bf16x8*)(Kc + l32 * 512 + pc * 16);
            sfB = __builtin_amdgcn_mfma_f32_32x32x16_bf16(kf, qf[ks], sfB, 0, 0, 0);
        }
        __builtin_amdgcn_s_setprio(0);

        float sv[16];
        #pragma unroll
        for (int r = 0; r < 16; ++r) sv[r] = sfA[r] + sfB[r];

        // tree max (depth 4) + cross-half
        float m0a = fmaxf(sv[0], sv[1]),  m1a = fmaxf(sv[2], sv[3]);
        float m2a = fmaxf(sv[4], sv[5]),  m3a = fmaxf(sv[6], sv[7]);
        float m4a = fmaxf(sv[8], sv[9]),  m5a = fmaxf(sv[10], sv[11]);
        float m6a = fmaxf(sv[12], sv[13]), m7a = fmaxf(sv[14], sv[15]);
        float m0b = fmaxf(m0a, m1a), m1b = fmaxf(m2a, m3a);
        float m2b = fmaxf(m4a, m5a), m3b = fmaxf(m6a, m7a);
        float tm = fmaxf(fmaxf(m0b, m1b), fmaxf(m2b, m3b));
        tm = fmaxf(tm, __shfl_xor(tm, 32, 64));
        tm *= scale;
        if (__any(tm > mr + 8.f)) {
            const float mn = fmaxf(mr, tm);
            const float al = __expf(mr - mn);
            mr = mn;
            sr *= al;
            #pragma unroll
            for (int ct = 0; ct < 8; ++ct)
                #pragma unroll
                for (int r = 0; r < 16; ++r) acc[ct][r] *= al;
        }
        float p[16];
        #pragma unroll
        for (int r = 0; r < 16; ++r)
            p[r] = __expf(sv[r] * scale - mr);
        // tree sum (depth 4) + cross-half
        float s0a = p[0] + p[1],  s1a = p[2] + p[3];
        float s2a = p[4] + p[5],  s3a = p[6] + p[7];
        float s4a = p[8] + p[9],  s5a = p[10] + p[11];
        float s6a = p[12] + p[13], s7a = p[14] + p[15];
        float sacc = ((s0a + s1a) + (s2a + s3a)) + ((s4a + s5a) + (s6a + s7a));
        sacc += __shfl_xor(sacc, 32, 64);
        sr += sacc;

        // zero-shuffle PV B-frags: pb[kstep] = p[8*kstep .. 8*kstep+7]
        bf16x8 pb[2];
        #pragma unroll
        for (int kstep = 0; kstep < 2; ++kstep) {
            union { unsigned u[4]; bf16x8 v; } uu;
            #pragma unroll
            for (int w = 0; w < 4; ++w)
                uu.u[w] = pack2(p[8 * kstep + 2 * w], p[8 * kstep + 2 * w + 1]);
            pb[kstep] = uu.v;
        }

        // H^T += V^T P
        __builtin_amdgcn_s_setprio(1);
        #pragma unroll
        for (int ct = 0; ct < 8; ++ct) {
            const int j = ct * 8 + (l32 >> 2);
            #pragma unroll
            for (int kstep = 0; kstep < 2; ++kstep) {
                const int u = ((l32 & 3) << 2) | (2 * kstep + h2);
                const int phys = u ^ (j & 7);
                bf16x8 vf = *(const bf16x8*)(Vc + j * 256 + phys * 16);
                acc[ct] = __builtin_amdgcn_mfma_f32_32x32x16_bf16(vf, pb[kstep], acc[ct], 0, 0, 0);
            }
        }
        __builtin_amdgcn_s_setprio(0);
        __syncthreads();  // drains vmcnt: tiles 2s+2,2s+3 resident; slots reusable
    }

    // pair merge: upper (half=1) dumps partials to LDS; lower merges + stores
    float* const ex = (float*)smem;
    const int slot = (qgrp * 64 + ln) * 136;
    if (half) {
        float* dst = ex + slot;
        #pragma unroll
        for (int ct = 0; ct < 8; ++ct)
            #pragma unroll
            for (int rr = 0; rr < 4; ++rr) {
                f32x4 v = {acc[ct][rr * 4 + 0], acc[ct][rr * 4 + 1],
                           acc[ct][rr * 4 + 2], acc[ct][rr * 4 + 3]};
                *(f32x4*)(dst + ct * 16 + rr * 4) = v;
            }
        dst[128] = mr;
        dst[129] = sr;
    }
    __syncthreads();
    if (!half) {
        const float* src = ex + slot;
        const float mb = src[128], lb = src[129];
        const float m = fmaxf(mr, mb);
        float fa = __expf(mr - m), fb = __expf(mb - m);
        const float inv = 1.0f / (sr * fa + lb * fb);
        fa *= inv; fb *= inv;
        __hip_bfloat16* hp = Ht + ((size_t)b * NN + n0 + qgrp * 32 + l32) * NC;
        #pragma unroll
        for (int ct = 0; ct < 8; ++ct)
            #pragma unroll
            for (int ss = 0; ss < 4; ++ss) {
                const float o0 = acc[ct][ss * 4 + 0] * fa + src[ct * 16 + ss * 4 + 0] * fb;
                const float o1 = acc[ct][ss * 4 + 1] * fa + src[ct * 16 + ss * 4 + 1] * fb;
                const float o2 = acc[ct][ss * 4 + 2] * fa + src[ct * 16 + ss * 4 + 2] * fb;
                const float o3 = acc[ct][ss * 4 + 3] * fa + src[ct * 16 + ss * 4 + 3] * fb;
                uint2 v;
                v.x = pack2(o0, o1);
                v.y = pack2(o2, o3);
                *(uint2*)(hp + ct * 32 + ss * 8 + h2 * 4) = v;
            }
    }
}

// ---------------------------------------------------------------------------
// Kernel 3: output projection GEMM (bf16 MFMA) + bias + skip — unchanged.
// ---------------------------------------------------------------------------
__global__ __launch_bounds__(256, 2) void out_gemm_kernel(
    const __hip_bfloat16* __restrict__ Ht, const float* __restrict__ w_out,
    const float* __restrict__ b_out, const float* __restrict__ x,
    float* __restrict__ out)
{
    __shared__ char smem[65536];
    char* const A0 = smem;
    char* const A1 = smem + 16384;
    char* const B0 = smem + 32768;
    char* const B1 = smem + 49152;

    const int t  = threadIdx.x;
    const int wv = t >> 6, ln = t & 63, lo = ln & 15, hi = ln >> 4;
    const int wm = wv >> 1, wn = wv & 1;
    const int n0 = blockIdx.x * 128, o0 = blockIdx.y * 128, b = blockIdx.z;

    const float* Ag = w_out + (size_t)o0 * NC;
    const __hip_bfloat16* Bg = Ht + ((size_t)b * NN + n0) * NC;

    f32x4 acc[4][4];
    #pragma unroll
    for (int i = 0; i < 4; ++i)
        #pragma unroll
        for (int j = 0; j < 4; ++j) acc[i][j] = (f32x4){0.f, 0.f, 0.f, 0.f};

    int ra[4], rb[4];
    #pragma unroll
    for (int f = 0; f < 4; ++f) { ra[f] = wm * 64 + f * 16 + lo; rb[f] = wn * 64 + f * 16 + lo; }

    stage_ab(Bg, Ag, B0, A0, 0, t);
    __syncthreads();
    #pragma unroll
    for (int ks = 0; ks < 4; ++ks) {
        char* Ac = (ks & 1) ? A1 : A0;
        char* Bc = (ks & 1) ? B1 : B0;
        if (ks < 3)
            stage_ab(Bg, Ag, (ks & 1) ? B0 : B1, (ks & 1) ? A0 : A1, ks + 1, t);
        #pragma unroll
        for (int kk = 0; kk < 2; ++kk) {
            bf16x8 av[4], bv[4];
            #pragma unroll
            for (int f = 0; f < 4; ++f) {
                av[f] = *(const bf16x8*)(Ac + ra[f] * 128 + (((kk << 2) | hi) ^ (ra[f] & 7)) * 16);
                bv[f] = *(const bf16x8*)(Bc + rb[f] * 128 + (((kk << 2) | hi) ^ (rb[f] & 7)) * 16);
            }
            #pragma unroll
            for (int fm = 0; fm < 4; ++fm)
                #pragma unroll
                for (int fn = 0; fn < 4; ++fn)
                    acc[fm][fn] = __builtin_amdgcn_mfma_f32_16x16x32_bf16(
                        av[fm], bv[fn], acc[fm][fn], 0, 0, 0);
        }
        __syncthreads();
    }

    #pragma unroll
    for (int fm = 0; fm < 4; ++fm) {
        #pragma unroll
        for (int r = 0; r < 4; ++r) {
            const int o = o0 + wm * 64 + fm * 16 + hi * 4 + r;
            const float bo = b_out[o];
            const size_t rowg = ((size_t)b * NC + o) * NN + n0;
            #pragma unroll
            for (int fn = 0; fn < 4; ++fn) {
                const size_t gi = rowg + wn * 64 + fn * 16 + lo;
                out[gi] = acc[fm][fn][r] + bo + x[gi];
            }
        }
    }
}

// ---------------------------------------------------------------------------
extern "C" void kernel_launch(void* const* d_in, const int* in_sizes, int n_in,
                              void* d_out, int out_size, void* d_ws, size_t ws_size,
                              hipStream_t stream) {
    const float* x     = (const float*)d_in[0];
    const float* w_in  = (const float*)d_in[1];
    const float* b_in  = (const float*)d_in[2];
    const float* w_out = (const float*)d_in[3];
    const float* b_out = (const float*)d_in[4];
    float* out = (float*)d_out;

    if (ws_size < (size_t)64 * 1024 * 1024) return;  // fail loud
    char* ws = (char*)d_ws;
    __hip_bfloat16* Qt = (__hip_bfloat16*)(ws);
    __hip_bfloat16* Kt = (__hip_bfloat16*)(ws + ((size_t)16 << 20));
    __hip_bfloat16* Vx = (__hip_bfloat16*)(ws + ((size_t)32 << 20));
    __hip_bfloat16* Xt = (__hip_bfloat16*)(ws + ((size_t)48 << 20));  // aliased as Ht
    __hip_bfloat16* Ht = Xt;  // Xt dead after qkv_gemm

    xpose_kernel<<<dim3(16, 4, 32), 256, 0, stream>>>(x, Xt);
    qkv_gemm_kernel<<<dim3(8, 6, 32), 256, 0, stream>>>(Xt, w_in, b_in, Qt, Kt, Vx);
    attn_kernel<<<dim3(8, 32), 512, 0, stream>>>(Qt, Kt, Vx, Ht);
    out_gemm_kernel<<<dim3(8, 2, 32), 256, 0, stream>>>(Ht, w_out, b_out, x, out);
}

// Round 9
// 92.648 us; speedup vs baseline: 1.1914x; 1.1674x over previous
//
#include <hip/hip_runtime.h>
#include <hip/hip_bf16.h>

typedef __attribute__((ext_vector_type(8))) short bf16x8;
typedef __attribute__((ext_vector_type(4))) float f32x4;
typedef __attribute__((ext_vector_type(16))) float f32x16;
typedef long long i64;

#define NB 32
#define NC 256
#define NN 1024

__device__ __forceinline__ unsigned pack2(float a, float b) {
    __hip_bfloat16 ha = __float2bfloat16(a), hb = __float2bfloat16(b);
    unsigned short ua = *(unsigned short*)&ha, ub = *(unsigned short*)&hb;
    return (unsigned)ua | ((unsigned)ub << 16);
}

__device__ __forceinline__ float bflo(unsigned u) {
    union { unsigned i; float f; } x; x.i = u << 16; return x.f;
}
__device__ __forceinline__ float bfhi(unsigned u) {
    union { unsigned i; float f; } x; x.i = u & 0xffff0000u; return x.f;
}
// 4 floats -> 4 OCP e4m3 bytes (little-endian order a,b,c,d)
__device__ __forceinline__ unsigned fp8x4(float a, float b, float c, float d) {
    int w = __builtin_amdgcn_cvt_pk_fp8_f32(a, b, 0, false);
    w = __builtin_amdgcn_cvt_pk_fp8_f32(c, d, w, true);
    return (unsigned)w;
}

// async global->LDS, 16B per lane; LDS dest = wave-uniform base + lane*16
__device__ __forceinline__ void glds16(const void* g, void* lds) {
    __builtin_amdgcn_global_load_lds(
        (const __attribute__((address_space(1))) unsigned int*)g,
        (__attribute__((address_space(3))) unsigned int*)lds, 16, 0, 0);
}

// ---------------------------------------------------------------------------
// Kernel 0: transpose+cast  x[b][c][n] f32 -> Xt[b][n][c] bf16
// ---------------------------------------------------------------------------
__global__ __launch_bounds__(256) void xpose_kernel(
    const float* __restrict__ x, __hip_bfloat16* __restrict__ Xt)
{
    __shared__ float Ls[64 * 67];
    const int t = threadIdx.x;
    const int n0 = blockIdx.x * 64, c0 = blockIdx.y * 64, b = blockIdx.z;
    const int cl = t >> 4, nl = (t & 15) * 4;
    const float* xb = x + ((size_t)b * NC + c0) * NN + n0;
    #pragma unroll
    for (int q4 = 0; q4 < 4; ++q4) {
        const int c = cl + q4 * 16;
        const float4 v = *(const float4*)(xb + (size_t)c * NN + nl);
        Ls[(nl + 0) * 67 + c] = v.x;
        Ls[(nl + 1) * 67 + c] = v.y;
        Ls[(nl + 2) * 67 + c] = v.z;
        Ls[(nl + 3) * 67 + c] = v.w;
    }
    __syncthreads();
    #pragma unroll
    for (int p = 0; p < 2; ++p) {
        const int idx = p * 256 + t, n = idx >> 3, cs = idx & 7;
        const float* r = &Ls[n * 67 + cs * 8];
        uint4 o;
        o.x = pack2(r[0], r[1]); o.y = pack2(r[2], r[3]);
        o.z = pack2(r[4], r[5]); o.w = pack2(r[6], r[7]);
        *(uint4*)(Xt + ((size_t)b * NN + n0 + n) * NC + c0 + cs * 8) = o;
    }
}

// ---------------------------------------------------------------------------
// Shared GEMM staging (element-traced swizzle; unchanged).
// ---------------------------------------------------------------------------
__device__ __forceinline__ void stage_ab(const __hip_bfloat16* __restrict__ Ag,
                                         const float* __restrict__ Bg,
                                         char* Ad, char* Bd, int ks, int t)
{
    const int srow = t >> 3, spch = t & 7;
    #pragma unroll
    for (int it = 0; it < 4; ++it) {
        const int row = it * 32 + srow;
        const int sw  = row & 7;
        glds16(Ag + (size_t)row * NC + ks * 64 + ((spch ^ sw) << 3),
               Ad + (it * 256 + t) * 16);
        const float* wp = Bg + (size_t)row * NC + ks * 64 + (spch << 3);
        const float4 u0 = *(const float4*)wp;
        const float4 u1 = *(const float4*)(wp + 4);
        uint4 pk;
        pk.x = pack2(u0.x, u0.y); pk.y = pack2(u0.z, u0.w);
        pk.z = pack2(u1.x, u1.y); pk.w = pack2(u1.z, u1.w);
        *(uint4*)(Bd + row * 128 + ((spch ^ sw) << 4)) = pk;
    }
}

// ---------------------------------------------------------------------------
// Kernel 1: QKV projection GEMM (bf16 MFMA); epilogue emits fp8 e4m3:
//   Qt8/Kt8: [b][n][c] fp8 (256B rows); Vf8: [b][g=n/8][c][8 keys] fp8.
// FIXED (r8 bug): Q/K fp8 copy-out now writes ONLY this block's 128-c half
//   (p<4, row=idx>>3, ch=idx&7) — no cross-block overwrite, no OOB Ls read.
// ---------------------------------------------------------------------------
__global__ __launch_bounds__(256, 2) void qkv_gemm_kernel(
    const __hip_bfloat16* __restrict__ Xt, const float* __restrict__ w_in,
    const float* __restrict__ b_in, unsigned char* __restrict__ Qt8,
    unsigned char* __restrict__ Kt8, unsigned char* __restrict__ Vf8)
{
    __shared__ char smem[65536];
    char* const A0 = smem;
    char* const A1 = smem + 16384;
    char* const B0 = smem + 32768;
    char* const B1 = smem + 49152;

    const int t  = threadIdx.x;
    const int wv = t >> 6, ln = t & 63, lo = ln & 15, hi = ln >> 4;
    const int wm = wv >> 1, wn = wv & 1;
    const int n0 = blockIdx.x * 128, o0 = blockIdx.y * 128, b = blockIdx.z;

    const __hip_bfloat16* Ag = Xt + ((size_t)b * NN + n0) * NC;
    const float* Bg = w_in + (size_t)o0 * NC;

    f32x4 acc[4][4];
    #pragma unroll
    for (int i = 0; i < 4; ++i)
        #pragma unroll
        for (int j = 0; j < 4; ++j) acc[i][j] = (f32x4){0.f, 0.f, 0.f, 0.f};

    int ra[4], rb[4];
    #pragma unroll
    for (int f = 0; f < 4; ++f) { ra[f] = wm * 64 + f * 16 + lo; rb[f] = wn * 64 + f * 16 + lo; }

    stage_ab(Ag, Bg, A0, B0, 0, t);
    __syncthreads();
    #pragma unroll
    for (int ks = 0; ks < 4; ++ks) {
        char* Ac = (ks & 1) ? A1 : A0;
        char* Bc = (ks & 1) ? B1 : B0;
        if (ks < 3)
            stage_ab(Ag, Bg, (ks & 1) ? A0 : A1, (ks & 1) ? B0 : B1, ks + 1, t);
        #pragma unroll
        for (int kk = 0; kk < 2; ++kk) {
            bf16x8 av[4], bv[4];
            #pragma unroll
            for (int f = 0; f < 4; ++f) {
                av[f] = *(const bf16x8*)(Ac + ra[f] * 128 + (((kk << 2) | hi) ^ (ra[f] & 7)) * 16);
                bv[f] = *(const bf16x8*)(Bc + rb[f] * 128 + (((kk << 2) | hi) ^ (rb[f] & 7)) * 16);
            }
            #pragma unroll
            for (int fm = 0; fm < 4; ++fm)
                #pragma unroll
                for (int fn = 0; fn < 4; ++fn)
                    acc[fm][fn] = __builtin_amdgcn_mfma_f32_16x16x32_bf16(
                        av[fm], bv[fn], acc[fm][fn], 0, 0, 0);
        }
        __syncthreads();
    }

    float bias[4];
    #pragma unroll
    for (int fn = 0; fn < 4; ++fn) bias[fn] = b_in[o0 + wn * 64 + fn * 16 + lo];

    __hip_bfloat16* Ls = (__hip_bfloat16*)smem;  // [128][136] bf16
    if (o0 < 512) {
        #pragma unroll
        for (int fm = 0; fm < 4; ++fm)
            #pragma unroll
            for (int fn = 0; fn < 4; ++fn)
                #pragma unroll
                for (int r = 0; r < 4; ++r)
                    Ls[(wm * 64 + fm * 16 + hi * 4 + r) * 136 + wn * 64 + fn * 16 + lo] =
                        __float2bfloat16(acc[fm][fn][r] + bias[fn]);
        __syncthreads();
        unsigned char* dst = (o0 < 256) ? Qt8 : Kt8;
        const int oc = (o0 < 256) ? o0 : o0 - 256;
        #pragma unroll
        for (int p = 0; p < 4; ++p) {
            const int idx = p * 256 + t, row = idx >> 3, ch = idx & 7;  // 16-c chunks
            const unsigned* ls = (const unsigned*)&Ls[row * 136 + ch * 16];
            const uint4 a = *(const uint4*)ls;
            const uint4 b2 = *(const uint4*)(ls + 4);
            uint4 o;
            o.x = fp8x4(bflo(a.x), bfhi(a.x), bflo(a.y), bfhi(a.y));
            o.y = fp8x4(bflo(a.z), bfhi(a.z), bflo(a.w), bfhi(a.w));
            o.z = fp8x4(bflo(b2.x), bfhi(b2.x), bflo(b2.y), bfhi(b2.y));
            o.w = fp8x4(bflo(b2.z), bfhi(b2.z), bflo(b2.w), bfhi(b2.w));
            *(uint4*)(dst + ((size_t)b * NN + n0 + row) * 256 + oc + ch * 16) = o;
        }
    } else {
        #pragma unroll
        for (int fm = 0; fm < 4; ++fm)
            #pragma unroll
            for (int fn = 0; fn < 4; ++fn)
                #pragma unroll
                for (int r = 0; r < 4; ++r)
                    Ls[(wn * 64 + fn * 16 + lo) * 136 + wm * 64 + fm * 16 + hi * 4 + r] =
                        __float2bfloat16(acc[fm][fn][r] + bias[fn]);
        __syncthreads();
        // Vf8[b][g][c][8]: 8B per (g, c-row); coalesced over consecutive c
        #pragma unroll
        for (int p = 0; p < 8; ++p) {
            const int idx = p * 256 + t;
            const int ch = idx >> 7, cr = idx & 127;   // ch: 8-key group, cr: c row
            const unsigned* ls = (const unsigned*)&Ls[cr * 136 + ch * 8];
            const uint4 a = *(const uint4*)ls;
            uint2 o;
            o.x = fp8x4(bflo(a.x), bfhi(a.x), bflo(a.y), bfhi(a.y));
            o.y = fp8x4(bflo(a.z), bfhi(a.z), bflo(a.w), bfhi(a.w));
            const int g = (n0 >> 3) + ch;
            *(uint2*)(Vf8 + (((size_t)b * 128 + g) * 256 + (o0 - 512) + cr) * 8) = o;
        }
    }
}

// ---------------------------------------------------------------------------
// Kernel 2: flash attention v8 — fp8 e4m3 fragments, 32x32x16_fp8_fp8.
// Structure = v7 (8 waves: 4 qgrp x 2 half, KVBLK=32, 4 slots, pair-merge,
// K-row pi-permutation for zero-shuffle PV — layouts dtype-independent).
// Per-slot: K 8KB ([32 r][16 chunks16B], chunk swizzle pc = c16 ^ (r&15));
//           V 8KB (linear copy of Vf8[g0..g0+3][c][8] -> [kc][c][8B]).
// Frag reads are ds_read_b64 (8B): LDS traffic halved vs bf16.
// ---------------------------------------------------------------------------
__device__ __forceinline__ void stage_tile(const unsigned char* __restrict__ Kb,
                                           const unsigned char* __restrict__ Vb,
                                           char* Kd, char* Vd, int m0, int t)
{
    {   // K: 512 x 16B units, 1 per thread
        const int row = t >> 4, pc = t & 15;
        const int prow = (row & 19) | ((row & 4) << 1) | ((row & 8) >> 1); // pi
        const int sc = pc ^ (row & 15);
        glds16(Kb + (size_t)(m0 + prow) * 256 + sc * 16, Kd + t * 16);
    }
    {   // V: pure linear 8KB copy (global layout matches LDS layout)
        glds16(Vb + (size_t)(m0 >> 3) * 2048 + t * 16, Vd + t * 16);
    }
}

__global__ __launch_bounds__(512, 2) void attn_kernel(
    const unsigned char* __restrict__ Qt8, const unsigned char* __restrict__ Kt8,
    const unsigned char* __restrict__ Vf8, __hip_bfloat16* __restrict__ Ht)
{
    __shared__ char smem[139264];   // loop: K 4x8K | V 4x8K (64K); epilogue exch

    const int t  = threadIdx.x;
    const int wv = t >> 6, ln = t & 63;
    const int l32 = ln & 31, h2 = ln >> 5;
    const int qgrp = wv & 3, half = wv >> 2;
    const int wid = blockIdx.x + 8 * blockIdx.y;
    const int swz = (wid & 7) * 32 + (wid >> 3);       // XCD gets 4 batches
    const int qb = swz & 7, b = swz >> 3;
    const int n0 = qb * 128;
    const float scale = 0.0625f;  // 1/sqrt(256)

    const unsigned char* Kbase = Kt8 + (size_t)b * NN * 256;
    const unsigned char* Vbase = Vf8 + (size_t)b * 128 * 2048;

    // Q B-frags (fp8): q-col = n0 + qgrp*32 + l32; 8B per ks
    const unsigned char* qp = Qt8 + ((size_t)b * NN + n0 + qgrp * 32 + l32) * 256;
    i64 qf[16];
    #pragma unroll
    for (int ks = 0; ks < 16; ++ks)
        qf[ks] = *(const i64*)(qp + ks * 16 + h2 * 8);

    f32x16 acc[8];
    #pragma unroll
    for (int ct = 0; ct < 8; ++ct)
        #pragma unroll
        for (int r = 0; r < 16; ++r) acc[ct][r] = 0.f;
    float mr = 0.f;   // per-q running max (scaled units; defer-max)
    float sr = 0.f;   // per-q running denom

    #pragma unroll
    for (int tt = 0; tt < 4; ++tt)
        stage_tile(Kbase, Vbase, smem + tt * 8192, smem + 32768 + tt * 8192,
                   tt * 32, t);
    __syncthreads();   // drains vmcnt -> tiles 0..3 resident

    for (int s = 0; s < 16; ++s) {
        if (s < 15) {
            const int t2 = 2 * s + 2, t3 = 2 * s + 3;
            stage_tile(Kbase, Vbase, smem + (t2 & 3) * 8192,
                       smem + 32768 + (t2 & 3) * 8192, t2 * 32, t);
            stage_tile(Kbase, Vbase, smem + (t3 & 3) * 8192,
                       smem + 32768 + (t3 & 3) * 8192, t3 * 32, t);
        }
        const int tile = 2 * s + half;
        char* const Kc = smem + (tile & 3) * 8192;
        char* const Vc = smem + 32768 + (tile & 3) * 8192;

        // S^T = K Q^T : two independent 8-deep chains (fp8, K=16)
        f32x16 sfA, sfB;
        #pragma unroll
        for (int r = 0; r < 16; ++r) { sfA[r] = 0.f; sfB[r] = 0.f; }
        __builtin_amdgcn_s_setprio(1);
        #pragma unroll
        for (int ks = 0; ks < 8; ++ks) {
            const int pc = ks ^ (l32 & 15);
            const i64 kf = *(const i64*)(Kc + l32 * 256 + pc * 16 + h2 * 8);
            sfA = __builtin_amdgcn_mfma_f32_32x32x16_fp8_fp8(kf, qf[ks], sfA, 0, 0, 0);
        }
        #pragma unroll
        for (int ks = 8; ks < 16; ++ks) {
            const int pc = ks ^ (l32 & 15);
            const i64 kf = *(const i64*)(Kc + l32 * 256 + pc * 16 + h2 * 8);
            sfB = __builtin_amdgcn_mfma_f32_32x32x16_fp8_fp8(kf, qf[ks], sfB, 0, 0, 0);
        }
        __builtin_amdgcn_s_setprio(0);

        float sv[16];
        #pragma unroll
        for (int r = 0; r < 16; ++r) sv[r] = sfA[r] + sfB[r];

        // tree max + cross-half
        float m0a = fmaxf(sv[0], sv[1]),  m1a = fmaxf(sv[2], sv[3]);
        float m2a = fmaxf(sv[4], sv[5]),  m3a = fmaxf(sv[6], sv[7]);
        float m4a = fmaxf(sv[8], sv[9]),  m5a = fmaxf(sv[10], sv[11]);
        float m6a = fmaxf(sv[12], sv[13]), m7a = fmaxf(sv[14], sv[15]);
        float m0b = fmaxf(m0a, m1a), m1b = fmaxf(m2a, m3a);
        float m2b = fmaxf(m4a, m5a), m3b = fmaxf(m6a, m7a);
        float tm = fmaxf(fmaxf(m0b, m1b), fmaxf(m2b, m3b));
        tm = fmaxf(tm, __shfl_xor(tm, 32, 64));
        tm *= scale;
        if (__any(tm > mr + 8.f)) {
            const float mn = fmaxf(mr, tm);
            const float al = __expf(mr - mn);
            mr = mn;
            sr *= al;
            #pragma unroll
            for (int ct = 0; ct < 8; ++ct)
                #pragma unroll
                for (int r = 0; r < 16; ++r) acc[ct][r] *= al;
        }
        float p[16];
        #pragma unroll
        for (int r = 0; r < 16; ++r)
            p[r] = __expf(sv[r] * scale - mr);
        float s0a = p[0] + p[1],  s1a = p[2] + p[3];
        float s2a = p[4] + p[5],  s3a = p[6] + p[7];
        float s4a = p[8] + p[9],  s5a = p[10] + p[11];
        float s6a = p[12] + p[13], s7a = p[14] + p[15];
        float sacc = ((s0a + s1a) + (s2a + s3a)) + ((s4a + s5a) + (s6a + s7a));
        sacc += __shfl_xor(sacc, 32, 64);
        sr += sacc;

        // zero-shuffle PV B-frags (pi property): pb[kstep] = fp8(p[8k..8k+7])
        i64 pb[2];
        #pragma unroll
        for (int kstep = 0; kstep < 2; ++kstep) {
            union { unsigned u[2]; i64 l; } uu;
            uu.u[0] = fp8x4(p[8 * kstep + 0], p[8 * kstep + 1],
                            p[8 * kstep + 2], p[8 * kstep + 3]);
            uu.u[1] = fp8x4(p[8 * kstep + 4], p[8 * kstep + 5],
                            p[8 * kstep + 6], p[8 * kstep + 7]);
            pb[kstep] = uu.l;
        }

        // H^T += V^T P   (V rows = c channels; ds_read_b64, 2-way banks)
        __builtin_amdgcn_s_setprio(1);
        #pragma unroll
        for (int ct = 0; ct < 8; ++ct) {
            #pragma unroll
            for (int kstep = 0; kstep < 2; ++kstep) {
                const i64 vf = *(const i64*)(Vc + (2 * kstep + h2) * 2048 +
                                             (ct * 32 + l32) * 8);
                acc[ct] = __builtin_amdgcn_mfma_f32_32x32x16_fp8_fp8(vf, pb[kstep], acc[ct], 0, 0, 0);
            }
        }
        __builtin_amdgcn_s_setprio(0);
        __syncthreads();  // drains vmcnt: tiles 2s+2,2s+3 resident; slots reusable
    }

    // pair merge: upper (half=1) dumps partials to LDS; lower merges + stores
    float* const ex = (float*)smem;
    const int slot = (qgrp * 64 + ln) * 136;
    if (half) {
        float* dst = ex + slot;
        #pragma unroll
        for (int ct = 0; ct < 8; ++ct)
            #pragma unroll
            for (int rr = 0; rr < 4; ++rr) {
                f32x4 v = {acc[ct][rr * 4 + 0], acc[ct][rr * 4 + 1],
                           acc[ct][rr * 4 + 2], acc[ct][rr * 4 + 3]};
                *(f32x4*)(dst + ct * 16 + rr * 4) = v;
            }
        dst[128] = mr;
        dst[129] = sr;
    }
    __syncthreads();
    if (!half) {
        const float* src = ex + slot;
        const float mb = src[128], lb = src[129];
        const float m = fmaxf(mr, mb);
        float fa = __expf(mr - m), fb = __expf(mb - m);
        const float inv = 1.0f / (sr * fa + lb * fb);
        fa *= inv; fb *= inv;
        __hip_bfloat16* hp = Ht + ((size_t)b * NN + n0 + qgrp * 32 + l32) * NC;
        #pragma unroll
        for (int ct = 0; ct < 8; ++ct)
            #pragma unroll
            for (int ss = 0; ss < 4; ++ss) {
                const float o0 = acc[ct][ss * 4 + 0] * fa + src[ct * 16 + ss * 4 + 0] * fb;
                const float o1 = acc[ct][ss * 4 + 1] * fa + src[ct * 16 + ss * 4 + 1] * fb;
                const float o2 = acc[ct][ss * 4 + 2] * fa + src[ct * 16 + ss * 4 + 2] * fb;
                const float o3 = acc[ct][ss * 4 + 3] * fa + src[ct * 16 + ss * 4 + 3] * fb;
                uint2 v;
                v.x = pack2(o0, o1);
                v.y = pack2(o2, o3);
                *(uint2*)(hp + ct * 32 + ss * 8 + h2 * 4) = v;
            }
    }
}

// ---------------------------------------------------------------------------
// Kernel 3: output projection GEMM (bf16 MFMA) + bias + skip — unchanged.
// ---------------------------------------------------------------------------
__global__ __launch_bounds__(256, 2) void out_gemm_kernel(
    const __hip_bfloat16* __restrict__ Ht, const float* __restrict__ w_out,
    const float* __restrict__ b_out, const float* __restrict__ x,
    float* __restrict__ out)
{
    __shared__ char smem[65536];
    char* const A0 = smem;
    char* const A1 = smem + 16384;
    char* const B0 = smem + 32768;
    char* const B1 = smem + 49152;

    const int t  = threadIdx.x;
    const int wv = t >> 6, ln = t & 63, lo = ln & 15, hi = ln >> 4;
    const int wm = wv >> 1, wn = wv & 1;
    const int n0 = blockIdx.x * 128, o0 = blockIdx.y * 128, b = blockIdx.z;

    const float* Ag = w_out + (size_t)o0 * NC;
    const __hip_bfloat16* Bg = Ht + ((size_t)b * NN + n0) * NC;

    f32x4 acc[4][4];
    #pragma unroll
    for (int i = 0; i < 4; ++i)
        #pragma unroll
        for (int j = 0; j < 4; ++j) acc[i][j] = (f32x4){0.f, 0.f, 0.f, 0.f};

    int ra[4], rb[4];
    #pragma unroll
    for (int f = 0; f < 4; ++f) { ra[f] = wm * 64 + f * 16 + lo; rb[f] = wn * 64 + f * 16 + lo; }

    stage_ab(Bg, Ag, B0, A0, 0, t);
    __syncthreads();
    #pragma unroll
    for (int ks = 0; ks < 4; ++ks) {
        char* Ac = (ks & 1) ? A1 : A0;
        char* Bc = (ks & 1) ? B1 : B0;
        if (ks < 3)
            stage_ab(Bg, Ag, (ks & 1) ? B0 : B1, (ks & 1) ? A0 : A1, ks + 1, t);
        #pragma unroll
        for (int kk = 0; kk < 2; ++kk) {
            bf16x8 av[4], bv[4];
            #pragma unroll
            for (int f = 0; f < 4; ++f) {
                av[f] = *(const bf16x8*)(Ac + ra[f] * 128 + (((kk << 2) | hi) ^ (ra[f] & 7)) * 16);
                bv[f] = *(const bf16x8*)(Bc + rb[f] * 128 + (((kk << 2) | hi) ^ (rb[f] & 7)) * 16);
            }
            #pragma unroll
            for (int fm = 0; fm < 4; ++fm)
                #pragma unroll
                for (int fn = 0; fn < 4; ++fn)
                    acc[fm][fn] = __builtin_amdgcn_mfma_f32_16x16x32_bf16(
                        av[fm], bv[fn], acc[fm][fn], 0, 0, 0);
        }
        __syncthreads();
    }

    #pragma unroll
    for (int fm = 0; fm < 4; ++fm) {
        #pragma unroll
        for (int r = 0; r < 4; ++r) {
            const int o = o0 + wm * 64 + fm * 16 + hi * 4 + r;
            const float bo = b_out[o];
            const size_t rowg = ((size_t)b * NC + o) * NN + n0;
            #pragma unroll
            for (int fn = 0; fn < 4; ++fn) {
                const size_t gi = rowg + wn * 64 + fn * 16 + lo;
                out[gi] = acc[fm][fn][r] + bo + x[gi];
            }
        }
    }
}

// ---------------------------------------------------------------------------
extern "C" void kernel_launch(void* const* d_in, const int* in_sizes, int n_in,
                              void* d_out, int out_size, void* d_ws, size_t ws_size,
                              hipStream_t stream) {
    const float* x     = (const float*)d_in[0];
    const float* w_in  = (const float*)d_in[1];
    const float* b_in  = (const float*)d_in[2];
    const float* w_out = (const float*)d_in[3];
    const float* b_out = (const float*)d_in[4];
    float* out = (float*)d_out;

    if (ws_size < (size_t)64 * 1024 * 1024) return;  // fail loud
    char* ws = (char*)d_ws;
    unsigned char* Qt8 = (unsigned char*)(ws);                       // 8 MB
    unsigned char* Kt8 = (unsigned char*)(ws + ((size_t)8 << 20));   // 8 MB
    unsigned char* Vf8 = (unsigned char*)(ws + ((size_t)16 << 20));  // 8 MB
    __hip_bfloat16* Ht = (__hip_bfloat16*)(ws + ((size_t)32 << 20)); // 16 MB
    __hip_bfloat16* Xt = (__hip_bfloat16*)(ws + ((size_t)48 << 20)); // 16 MB

    xpose_kernel<<<dim3(16, 4, 32), 256, 0, stream>>>(x, Xt);
    qkv_gemm_kernel<<<dim3(8, 6, 32), 256, 0, stream>>>(Xt, w_in, b_in, Qt8, Kt8, Vf8);
    attn_kernel<<<dim3(8, 32), 512, 0, stream>>>(Qt8, Kt8, Vf8, Ht);
    out_gemm_kernel<<<dim3(8, 2, 32), 256, 0, stream>>>(Ht, w_out, b_out, x, out);
}

// Round 10
// 88.031 us; speedup vs baseline: 1.2539x; 1.0525x over previous
//
#include <hip/hip_runtime.h>
#include <hip/hip_bf16.h>

typedef __attribute__((ext_vector_type(8))) short bf16x8;
typedef __attribute__((ext_vector_type(4))) float f32x4;
typedef __attribute__((ext_vector_type(16))) float f32x16;
typedef long long i64;

#define NB 32
#define NC 256
#define NN 1024

__device__ __forceinline__ unsigned pack2(float a, float b) {
    __hip_bfloat16 ha = __float2bfloat16(a), hb = __float2bfloat16(b);
    unsigned short ua = *(unsigned short*)&ha, ub = *(unsigned short*)&hb;
    return (unsigned)ua | ((unsigned)ub << 16);
}

__device__ __forceinline__ float bflo(unsigned u) {
    union { unsigned i; float f; } x; x.i = u << 16; return x.f;
}
__device__ __forceinline__ float bfhi(unsigned u) {
    union { unsigned i; float f; } x; x.i = u & 0xffff0000u; return x.f;
}
// 4 floats -> 4 OCP e4m3 bytes (little-endian order a,b,c,d)
__device__ __forceinline__ unsigned fp8x4(float a, float b, float c, float d) {
    int w = __builtin_amdgcn_cvt_pk_fp8_f32(a, b, 0, false);
    w = __builtin_amdgcn_cvt_pk_fp8_f32(c, d, w, true);
    return (unsigned)w;
}

// async global->LDS, 16B per lane; LDS dest = wave-uniform base + lane*16
__device__ __forceinline__ void glds16(const void* g, void* lds) {
    __builtin_amdgcn_global_load_lds(
        (const __attribute__((address_space(1))) unsigned int*)g,
        (__attribute__((address_space(3))) unsigned int*)lds, 16, 0, 0);
}

// ---------------------------------------------------------------------------
// Kernel 0: transpose+cast  x[b][c][n] f32 -> Xt[b][n][c] bf16  (unchanged)
// ---------------------------------------------------------------------------
__global__ __launch_bounds__(256) void xpose_kernel(
    const float* __restrict__ x, __hip_bfloat16* __restrict__ Xt)
{
    __shared__ float Ls[64 * 67];
    const int t = threadIdx.x;
    const int n0 = blockIdx.x * 64, c0 = blockIdx.y * 64, b = blockIdx.z;
    const int cl = t >> 4, nl = (t & 15) * 4;
    const float* xb = x + ((size_t)b * NC + c0) * NN + n0;
    #pragma unroll
    for (int q4 = 0; q4 < 4; ++q4) {
        const int c = cl + q4 * 16;
        const float4 v = *(const float4*)(xb + (size_t)c * NN + nl);
        Ls[(nl + 0) * 67 + c] = v.x;
        Ls[(nl + 1) * 67 + c] = v.y;
        Ls[(nl + 2) * 67 + c] = v.z;
        Ls[(nl + 3) * 67 + c] = v.w;
    }
    __syncthreads();
    #pragma unroll
    for (int p = 0; p < 2; ++p) {
        const int idx = p * 256 + t, n = idx >> 3, cs = idx & 7;
        const float* r = &Ls[n * 67 + cs * 8];
        uint4 o;
        o.x = pack2(r[0], r[1]); o.y = pack2(r[2], r[3]);
        o.z = pack2(r[4], r[5]); o.w = pack2(r[6], r[7]);
        *(uint4*)(Xt + ((size_t)b * NN + n0 + n) * NC + c0 + cs * 8) = o;
    }
}

// ---------------------------------------------------------------------------
// Shared GEMM staging (element-traced swizzle; unchanged).
// ---------------------------------------------------------------------------
__device__ __forceinline__ void stage_ab(const __hip_bfloat16* __restrict__ Ag,
                                         const float* __restrict__ Bg,
                                         char* Ad, char* Bd, int ks, int t)
{
    const int srow = t >> 3, spch = t & 7;
    #pragma unroll
    for (int it = 0; it < 4; ++it) {
        const int row = it * 32 + srow;
        const int sw  = row & 7;
        glds16(Ag + (size_t)row * NC + ks * 64 + ((spch ^ sw) << 3),
               Ad + (it * 256 + t) * 16);
        const float* wp = Bg + (size_t)row * NC + ks * 64 + (spch << 3);
        const float4 u0 = *(const float4*)wp;
        const float4 u1 = *(const float4*)(wp + 4);
        uint4 pk;
        pk.x = pack2(u0.x, u0.y); pk.y = pack2(u0.z, u0.w);
        pk.z = pack2(u1.x, u1.y); pk.w = pack2(u1.z, u1.w);
        *(uint4*)(Bd + row * 128 + ((spch ^ sw) << 4)) = pk;
    }
}

// ---------------------------------------------------------------------------
// Kernel 1: QKV projection GEMM (bf16 MFMA); fp8 epilogue (r9-fixed, unchanged)
// ---------------------------------------------------------------------------
__global__ __launch_bounds__(256, 2) void qkv_gemm_kernel(
    const __hip_bfloat16* __restrict__ Xt, const float* __restrict__ w_in,
    const float* __restrict__ b_in, unsigned char* __restrict__ Qt8,
    unsigned char* __restrict__ Kt8, unsigned char* __restrict__ Vf8)
{
    __shared__ char smem[65536];
    char* const A0 = smem;
    char* const A1 = smem + 16384;
    char* const B0 = smem + 32768;
    char* const B1 = smem + 49152;

    const int t  = threadIdx.x;
    const int wv = t >> 6, ln = t & 63, lo = ln & 15, hi = ln >> 4;
    const int wm = wv >> 1, wn = wv & 1;
    const int n0 = blockIdx.x * 128, o0 = blockIdx.y * 128, b = blockIdx.z;

    const __hip_bfloat16* Ag = Xt + ((size_t)b * NN + n0) * NC;
    const float* Bg = w_in + (size_t)o0 * NC;

    f32x4 acc[4][4];
    #pragma unroll
    for (int i = 0; i < 4; ++i)
        #pragma unroll
        for (int j = 0; j < 4; ++j) acc[i][j] = (f32x4){0.f, 0.f, 0.f, 0.f};

    int ra[4], rb[4];
    #pragma unroll
    for (int f = 0; f < 4; ++f) { ra[f] = wm * 64 + f * 16 + lo; rb[f] = wn * 64 + f * 16 + lo; }

    stage_ab(Ag, Bg, A0, B0, 0, t);
    __syncthreads();
    #pragma unroll
    for (int ks = 0; ks < 4; ++ks) {
        char* Ac = (ks & 1) ? A1 : A0;
        char* Bc = (ks & 1) ? B1 : B0;
        if (ks < 3)
            stage_ab(Ag, Bg, (ks & 1) ? A0 : A1, (ks & 1) ? B0 : B1, ks + 1, t);
        #pragma unroll
        for (int kk = 0; kk < 2; ++kk) {
            bf16x8 av[4], bv[4];
            #pragma unroll
            for (int f = 0; f < 4; ++f) {
                av[f] = *(const bf16x8*)(Ac + ra[f] * 128 + (((kk << 2) | hi) ^ (ra[f] & 7)) * 16);
                bv[f] = *(const bf16x8*)(Bc + rb[f] * 128 + (((kk << 2) | hi) ^ (rb[f] & 7)) * 16);
            }
            #pragma unroll
            for (int fm = 0; fm < 4; ++fm)
                #pragma unroll
                for (int fn = 0; fn < 4; ++fn)
                    acc[fm][fn] = __builtin_amdgcn_mfma_f32_16x16x32_bf16(
                        av[fm], bv[fn], acc[fm][fn], 0, 0, 0);
        }
        __syncthreads();
    }

    float bias[4];
    #pragma unroll
    for (int fn = 0; fn < 4; ++fn) bias[fn] = b_in[o0 + wn * 64 + fn * 16 + lo];

    __hip_bfloat16* Ls = (__hip_bfloat16*)smem;  // [128][136] bf16
    if (o0 < 512) {
        #pragma unroll
        for (int fm = 0; fm < 4; ++fm)
            #pragma unroll
            for (int fn = 0; fn < 4; ++fn)
                #pragma unroll
                for (int r = 0; r < 4; ++r)
                    Ls[(wm * 64 + fm * 16 + hi * 4 + r) * 136 + wn * 64 + fn * 16 + lo] =
                        __float2bfloat16(acc[fm][fn][r] + bias[fn]);
        __syncthreads();
        unsigned char* dst = (o0 < 256) ? Qt8 : Kt8;
        const int oc = (o0 < 256) ? o0 : o0 - 256;
        #pragma unroll
        for (int p = 0; p < 4; ++p) {
            const int idx = p * 256 + t, row = idx >> 3, ch = idx & 7;  // 16-c chunks
            const unsigned* ls = (const unsigned*)&Ls[row * 136 + ch * 16];
            const uint4 a = *(const uint4*)ls;
            const uint4 b2 = *(const uint4*)(ls + 4);
            uint4 o;
            o.x = fp8x4(bflo(a.x), bfhi(a.x), bflo(a.y), bfhi(a.y));
            o.y = fp8x4(bflo(a.z), bfhi(a.z), bflo(a.w), bfhi(a.w));
            o.z = fp8x4(bflo(b2.x), bfhi(b2.x), bflo(b2.y), bfhi(b2.y));
            o.w = fp8x4(bflo(b2.z), bfhi(b2.z), bflo(b2.w), bfhi(b2.w));
            *(uint4*)(dst + ((size_t)b * NN + n0 + row) * 256 + oc + ch * 16) = o;
        }
    } else {
        #pragma unroll
        for (int fm = 0; fm < 4; ++fm)
            #pragma unroll
            for (int fn = 0; fn < 4; ++fn)
                #pragma unroll
                for (int r = 0; r < 4; ++r)
                    Ls[(wn * 64 + fn * 16 + lo) * 136 + wm * 64 + fm * 16 + hi * 4 + r] =
                        __float2bfloat16(acc[fm][fn][r] + bias[fn]);
        __syncthreads();
        // Vf8[b][g][c][8]: 8B per (g, c-row); coalesced over consecutive c
        #pragma unroll
        for (int p = 0; p < 8; ++p) {
            const int idx = p * 256 + t;
            const int ch = idx >> 7, cr = idx & 127;   // ch: 8-key group, cr: c row
            const unsigned* ls = (const unsigned*)&Ls[cr * 136 + ch * 8];
            const uint4 a = *(const uint4*)ls;
            uint2 o;
            o.x = fp8x4(bflo(a.x), bfhi(a.x), bflo(a.y), bfhi(a.y));
            o.y = fp8x4(bflo(a.z), bfhi(a.z), bflo(a.w), bfhi(a.w));
            const int g = (n0 >> 3) + ch;
            *(uint2*)(Vf8 + (((size_t)b * 128 + g) * 256 + (o0 - 512) + cr) * 8) = o;
        }
    }
}

// ---------------------------------------------------------------------------
// Kernel 2: flash attention v9 — fp8 loop (r9, unchanged) + FUSED output
// projection epilogue: H stays in LDS, out = W_out*H^T + b_out + x written
// directly (out_gemm kernel and Ht buffer eliminated).
// Epilogue LDS plan (loop slots dead after final barrier):
//   ex   @0      : 128 slots x 132 f32 = 67584 B (pair-merge, 2 phases)
//   Hld  @69632  : [128 n][264 bf16]  = 67584 B (padded stride 528 B)
//   Wld  @0      : [128 o][264 bf16]  (overlays ex after merge done)
// GEMM: mfma_32x32x16_bf16(wf, hf) -> D row=o (A), col=n (B); per wave:
//   oT = wv>>1, nT in {2*(wv&1), +1}; two 128-o halves with W restage.
// ---------------------------------------------------------------------------
__device__ __forceinline__ void stage_tile(const unsigned char* __restrict__ Kb,
                                           const unsigned char* __restrict__ Vb,
                                           char* Kd, char* Vd, int m0, int t)
{
    {   // K: 512 x 16B units, 1 per thread
        const int row = t >> 4, pc = t & 15;
        const int prow = (row & 19) | ((row & 4) << 1) | ((row & 8) >> 1); // pi
        const int sc = pc ^ (row & 15);
        glds16(Kb + (size_t)(m0 + prow) * 256 + sc * 16, Kd + t * 16);
    }
    {   // V: pure linear 8KB copy (global layout matches LDS layout)
        glds16(Vb + (size_t)(m0 >> 3) * 2048 + t * 16, Vd + t * 16);
    }
}

__global__ __launch_bounds__(512, 2) void attn_kernel(
    const unsigned char* __restrict__ Qt8, const unsigned char* __restrict__ Kt8,
    const unsigned char* __restrict__ Vf8, const float* __restrict__ w_out,
    const float* __restrict__ b_out, const float* __restrict__ xg,
    float* __restrict__ out)
{
    __shared__ char smem[139264];

    const int t  = threadIdx.x;
    const int wv = t >> 6, ln = t & 63;
    const int l32 = ln & 31, h2 = ln >> 5;
    const int qgrp = wv & 3, half = wv >> 2;
    const int wid = blockIdx.x + 8 * blockIdx.y;
    const int swz = (wid & 7) * 32 + (wid >> 3);       // XCD gets 4 batches
    const int qb = swz & 7, b = swz >> 3;
    const int n0 = qb * 128;
    const float scale = 0.0625f;  // 1/sqrt(256)

    const unsigned char* Kbase = Kt8 + (size_t)b * NN * 256;
    const unsigned char* Vbase = Vf8 + (size_t)b * 128 * 2048;

    // Q B-frags (fp8): q-col = n0 + qgrp*32 + l32; 8B per ks
    const unsigned char* qp = Qt8 + ((size_t)b * NN + n0 + qgrp * 32 + l32) * 256;
    i64 qf[16];
    #pragma unroll
    for (int ks = 0; ks < 16; ++ks)
        qf[ks] = *(const i64*)(qp + ks * 16 + h2 * 8);

    f32x16 acc[8];
    #pragma unroll
    for (int ct = 0; ct < 8; ++ct)
        #pragma unroll
        for (int r = 0; r < 16; ++r) acc[ct][r] = 0.f;
    float mr = 0.f;
    float sr = 0.f;

    #pragma unroll
    for (int tt = 0; tt < 4; ++tt)
        stage_tile(Kbase, Vbase, smem + tt * 8192, smem + 32768 + tt * 8192,
                   tt * 32, t);
    __syncthreads();

    for (int s = 0; s < 16; ++s) {
        if (s < 15) {
            const int t2 = 2 * s + 2, t3 = 2 * s + 3;
            stage_tile(Kbase, Vbase, smem + (t2 & 3) * 8192,
                       smem + 32768 + (t2 & 3) * 8192, t2 * 32, t);
            stage_tile(Kbase, Vbase, smem + (t3 & 3) * 8192,
                       smem + 32768 + (t3 & 3) * 8192, t3 * 32, t);
        }
        const int tile = 2 * s + half;
        char* const Kc = smem + (tile & 3) * 8192;
        char* const Vc = smem + 32768 + (tile & 3) * 8192;

        // S^T = K Q^T : two independent 8-deep chains (fp8, K=16)
        f32x16 sfA, sfB;
        #pragma unroll
        for (int r = 0; r < 16; ++r) { sfA[r] = 0.f; sfB[r] = 0.f; }
        __builtin_amdgcn_s_setprio(1);
        #pragma unroll
        for (int ks = 0; ks < 8; ++ks) {
            const int pc = ks ^ (l32 & 15);
            const i64 kf = *(const i64*)(Kc + l32 * 256 + pc * 16 + h2 * 8);
            sfA = __builtin_amdgcn_mfma_f32_32x32x16_fp8_fp8(kf, qf[ks], sfA, 0, 0, 0);
        }
        #pragma unroll
        for (int ks = 8; ks < 16; ++ks) {
            const int pc = ks ^ (l32 & 15);
            const i64 kf = *(const i64*)(Kc + l32 * 256 + pc * 16 + h2 * 8);
            sfB = __builtin_amdgcn_mfma_f32_32x32x16_fp8_fp8(kf, qf[ks], sfB, 0, 0, 0);
        }
        __builtin_amdgcn_s_setprio(0);

        float sv[16];
        #pragma unroll
        for (int r = 0; r < 16; ++r) sv[r] = sfA[r] + sfB[r];

        float m0a = fmaxf(sv[0], sv[1]),  m1a = fmaxf(sv[2], sv[3]);
        float m2a = fmaxf(sv[4], sv[5]),  m3a = fmaxf(sv[6], sv[7]);
        float m4a = fmaxf(sv[8], sv[9]),  m5a = fmaxf(sv[10], sv[11]);
        float m6a = fmaxf(sv[12], sv[13]), m7a = fmaxf(sv[14], sv[15]);
        float m0b = fmaxf(m0a, m1a), m1b = fmaxf(m2a, m3a);
        float m2b = fmaxf(m4a, m5a), m3b = fmaxf(m6a, m7a);
        float tm = fmaxf(fmaxf(m0b, m1b), fmaxf(m2b, m3b));
        tm = fmaxf(tm, __shfl_xor(tm, 32, 64));
        tm *= scale;
        if (__any(tm > mr + 8.f)) {
            const float mn = fmaxf(mr, tm);
            const float al = __expf(mr - mn);
            mr = mn;
            sr *= al;
            #pragma unroll
            for (int ct = 0; ct < 8; ++ct)
                #pragma unroll
                for (int r = 0; r < 16; ++r) acc[ct][r] *= al;
        }
        float p[16];
        #pragma unroll
        for (int r = 0; r < 16; ++r)
            p[r] = __expf(sv[r] * scale - mr);
        float s0a = p[0] + p[1],  s1a = p[2] + p[3];
        float s2a = p[4] + p[5],  s3a = p[6] + p[7];
        float s4a = p[8] + p[9],  s5a = p[10] + p[11];
        float s6a = p[12] + p[13], s7a = p[14] + p[15];
        float sacc = ((s0a + s1a) + (s2a + s3a)) + ((s4a + s5a) + (s6a + s7a));
        sacc += __shfl_xor(sacc, 32, 64);
        sr += sacc;

        i64 pb[2];
        #pragma unroll
        for (int kstep = 0; kstep < 2; ++kstep) {
            union { unsigned u[2]; i64 l; } uu;
            uu.u[0] = fp8x4(p[8 * kstep + 0], p[8 * kstep + 1],
                            p[8 * kstep + 2], p[8 * kstep + 3]);
            uu.u[1] = fp8x4(p[8 * kstep + 4], p[8 * kstep + 5],
                            p[8 * kstep + 6], p[8 * kstep + 7]);
            pb[kstep] = uu.l;
        }

        __builtin_amdgcn_s_setprio(1);
        #pragma unroll
        for (int ct = 0; ct < 8; ++ct) {
            #pragma unroll
            for (int kstep = 0; kstep < 2; ++kstep) {
                const i64 vf = *(const i64*)(Vc + (2 * kstep + h2) * 2048 +
                                             (ct * 32 + l32) * 8);
                acc[ct] = __builtin_amdgcn_mfma_f32_32x32x16_fp8_fp8(vf, pb[kstep], acc[ct], 0, 0, 0);
            }
        }
        __builtin_amdgcn_s_setprio(0);
        __syncthreads();
    }

    // ---- pair merge (2 phases to fit LDS) -> H bf16 in LDS ----
    float* const ex = (float*)smem;                              // 128 x 132 f32
    __hip_bfloat16* const Hld = (__hip_bfloat16*)(smem + 69632); // [128][264]
    #pragma unroll
    for (int ph = 0; ph < 2; ++ph) {
        if (half == 1 && (qgrp >> 1) == ph) {
            float* dst = ex + ((qgrp & 1) * 64 + ln) * 132;
            #pragma unroll
            for (int ct = 0; ct < 8; ++ct)
                #pragma unroll
                for (int rr = 0; rr < 4; ++rr) {
                    f32x4 v = {acc[ct][rr * 4 + 0], acc[ct][rr * 4 + 1],
                               acc[ct][rr * 4 + 2], acc[ct][rr * 4 + 3]};
                    *(f32x4*)(dst + ct * 16 + rr * 4) = v;
                }
            dst[128] = mr;
            dst[129] = sr;
        }
        __syncthreads();
        if (half == 0 && (qgrp >> 1) == ph) {
            const float* src = ex + ((qgrp & 1) * 64 + ln) * 132;
            const float mb = src[128], lb = src[129];
            const float m = fmaxf(mr, mb);
            float fa = __expf(mr - m), fb = __expf(mb - m);
            const float inv = 1.0f / (sr * fa + lb * fb);
            fa *= inv; fb *= inv;
            __hip_bfloat16* hrow = Hld + (size_t)(qgrp * 32 + l32) * 264;
            #pragma unroll
            for (int ct = 0; ct < 8; ++ct)
                #pragma unroll
                for (int ss = 0; ss < 4; ++ss) {
                    const float o0 = acc[ct][ss * 4 + 0] * fa + src[ct * 16 + ss * 4 + 0] * fb;
                    const float o1 = acc[ct][ss * 4 + 1] * fa + src[ct * 16 + ss * 4 + 1] * fb;
                    const float o2 = acc[ct][ss * 4 + 2] * fa + src[ct * 16 + ss * 4 + 2] * fb;
                    const float o3 = acc[ct][ss * 4 + 3] * fa + src[ct * 16 + ss * 4 + 3] * fb;
                    uint2 v;
                    v.x = pack2(o0, o1);
                    v.y = pack2(o2, o3);
                    *(uint2*)(hrow + ct * 32 + ss * 8 + h2 * 4) = v;
                }
        }
        __syncthreads();
    }

    // ---- fused output projection: out = W_out * H^T + b_out + x ----
    __hip_bfloat16* const Wld = (__hip_bfloat16*)smem;   // [128][264], over ex
    const int oT = wv >> 1;
    const int nT0 = (wv & 1) * 2, nT1 = nT0 + 1;
    for (int oh = 0; oh < 2; ++oh) {
        // stage W_out rows oh*128..+127 as bf16 [o][264-pad]
        #pragma unroll
        for (int p = 0; p < 8; ++p) {
            const int idx = p * 512 + t;
            const int o = idx >> 5, ck = idx & 31;
            const float* wp = w_out + (size_t)(oh * 128 + o) * NC + ck * 8;
            const float4 u0 = *(const float4*)wp;
            const float4 u1 = *(const float4*)(wp + 4);
            uint4 pk;
            pk.x = pack2(u0.x, u0.y); pk.y = pack2(u0.z, u0.w);
            pk.z = pack2(u1.x, u1.y); pk.w = pack2(u1.z, u1.w);
            *(uint4*)((char*)Wld + (size_t)o * 528 + ck * 16) = pk;
        }
        __syncthreads();

        f32x16 oc0, oc1;
        #pragma unroll
        for (int r = 0; r < 16; ++r) { oc0[r] = 0.f; oc1[r] = 0.f; }
        __builtin_amdgcn_s_setprio(1);
        #pragma unroll
        for (int ks = 0; ks < 16; ++ks) {
            const int ck = ks * 2 + h2;
            bf16x8 wf = *(const bf16x8*)((char*)Wld + (size_t)(oT * 32 + l32) * 528 + ck * 16);
            bf16x8 hf0 = *(const bf16x8*)((char*)Hld + (size_t)(nT0 * 32 + l32) * 528 + ck * 16);
            bf16x8 hf1 = *(const bf16x8*)((char*)Hld + (size_t)(nT1 * 32 + l32) * 528 + ck * 16);
            oc0 = __builtin_amdgcn_mfma_f32_32x32x16_bf16(wf, hf0, oc0, 0, 0, 0);
            oc1 = __builtin_amdgcn_mfma_f32_32x32x16_bf16(wf, hf1, oc1, 0, 0, 0);
        }
        __builtin_amdgcn_s_setprio(0);

        #pragma unroll
        for (int r = 0; r < 16; ++r) {
            const int o = oh * 128 + oT * 32 + (r & 3) + 8 * (r >> 2) + 4 * h2;
            const float bo = b_out[o];
            const size_t rowg = ((size_t)b * NC + o) * NN + n0;
            const size_t g0 = rowg + nT0 * 32 + l32;
            const size_t g1 = rowg + nT1 * 32 + l32;
            out[g0] = oc0[r] + bo + xg[g0];
            out[g1] = oc1[r] + bo + xg[g1];
        }
        __syncthreads();   // W area reused next half
    }
}

// ---------------------------------------------------------------------------
extern "C" void kernel_launch(void* const* d_in, const int* in_sizes, int n_in,
                              void* d_out, int out_size, void* d_ws, size_t ws_size,
                              hipStream_t stream) {
    const float* x     = (const float*)d_in[0];
    const float* w_in  = (const float*)d_in[1];
    const float* b_in  = (const float*)d_in[2];
    const float* w_out = (const float*)d_in[3];
    const float* b_out = (const float*)d_in[4];
    float* out = (float*)d_out;

    if (ws_size < (size_t)64 * 1024 * 1024) return;  // fail loud
    char* ws = (char*)d_ws;
    unsigned char* Qt8 = (unsigned char*)(ws);                       // 8 MB
    unsigned char* Kt8 = (unsigned char*)(ws + ((size_t)8 << 20));   // 8 MB
    unsigned char* Vf8 = (unsigned char*)(ws + ((size_t)16 << 20));  // 8 MB
    __hip_bfloat16* Xt = (__hip_bfloat16*)(ws + ((size_t)24 << 20)); // 16.8 MB

    xpose_kernel<<<dim3(16, 4, 32), 256, 0, stream>>>(x, Xt);
    qkv_gemm_kernel<<<dim3(8, 6, 32), 256, 0, stream>>>(Xt, w_in, b_in, Qt8, Kt8, Vf8);
    attn_kernel<<<dim3(8, 32), 512, 0, stream>>>(Qt8, Kt8, Vf8, w_out, b_out, x, out);
}

// Round 11
// 84.371 us; speedup vs baseline: 1.3083x; 1.0434x over previous
//
#include <hip/hip_runtime.h>
#include <hip/hip_bf16.h>

typedef __attribute__((ext_vector_type(8))) short bf16x8;
typedef __attribute__((ext_vector_type(4))) float f32x4;
typedef __attribute__((ext_vector_type(16))) float f32x16;
typedef long long i64;

#define NB 32
#define NC 256
#define NN 1024

__device__ __forceinline__ unsigned pack2(float a, float b) {
    __hip_bfloat16 ha = __float2bfloat16(a), hb = __float2bfloat16(b);
    unsigned short ua = *(unsigned short*)&ha, ub = *(unsigned short*)&hb;
    return (unsigned)ua | ((unsigned)ub << 16);
}

__device__ __forceinline__ float bflo(unsigned u) {
    union { unsigned i; float f; } x; x.i = u << 16; return x.f;
}
__device__ __forceinline__ float bfhi(unsigned u) {
    union { unsigned i; float f; } x; x.i = u & 0xffff0000u; return x.f;
}
// 4 floats -> 4 OCP e4m3 bytes (little-endian order a,b,c,d)
__device__ __forceinline__ unsigned fp8x4(float a, float b, float c, float d) {
    int w = __builtin_amdgcn_cvt_pk_fp8_f32(a, b, 0, false);
    w = __builtin_amdgcn_cvt_pk_fp8_f32(c, d, w, true);
    return (unsigned)w;
}

// async global->LDS, 16B per lane; LDS dest = wave-uniform base + lane*16
__device__ __forceinline__ void glds16(const void* g, void* lds) {
    __builtin_amdgcn_global_load_lds(
        (const __attribute__((address_space(1))) unsigned int*)g,
        (__attribute__((address_space(3))) unsigned int*)lds, 16, 0, 0);
}

// ---------------------------------------------------------------------------
// Kernel 0: transpose+cast  x[b][c][n] f32 -> Xt8[b][n][c] fp8 e4m3
// ---------------------------------------------------------------------------
__global__ __launch_bounds__(256) void xpose_kernel(
    const float* __restrict__ x, unsigned char* __restrict__ Xt8)
{
    __shared__ float Ls[64 * 67];
    const int t = threadIdx.x;
    const int n0 = blockIdx.x * 64, c0 = blockIdx.y * 64, b = blockIdx.z;
    const int cl = t >> 4, nl = (t & 15) * 4;
    const float* xb = x + ((size_t)b * NC + c0) * NN + n0;
    #pragma unroll
    for (int q4 = 0; q4 < 4; ++q4) {
        const int c = cl + q4 * 16;
        const float4 v = *(const float4*)(xb + (size_t)c * NN + nl);
        Ls[(nl + 0) * 67 + c] = v.x;
        Ls[(nl + 1) * 67 + c] = v.y;
        Ls[(nl + 2) * 67 + c] = v.z;
        Ls[(nl + 3) * 67 + c] = v.w;
    }
    __syncthreads();
    #pragma unroll
    for (int p = 0; p < 2; ++p) {
        const int idx = p * 256 + t, n = idx >> 3, cs = idx & 7;
        const float* r = &Ls[n * 67 + cs * 8];
        uint2 o;
        o.x = fp8x4(r[0], r[1], r[2], r[3]);
        o.y = fp8x4(r[4], r[5], r[6], r[7]);
        *(uint2*)(Xt8 + ((size_t)b * NN + n0 + n) * 256 + c0 + cs * 8) = o;
    }
}

// ---------------------------------------------------------------------------
// Kernel 1: QKV projection GEMM — fp8 inputs (X fp8 via glds, W fp8 reg-cast),
// mfma_f32_16x16x32_fp8_fp8. Tiles [128 rows][64 c] fp8 = 8 KB each.
// Swizzle (16B units, 4/row): phys pc holds logical pc ^ (row&3); 8B frag
// read u_phys = u ^ (2*(row&3)) — low bit preserved so 16B staging intact.
// Trace: row5,u3: phys = 3^2=1; staged phys-unit0 holds logical 1 = bytes
// 16..31 = u{2,3} -> u3 at phys-u1 ✓.  Epilogue (bf16 Ls -> fp8 out) as r9.
// ---------------------------------------------------------------------------
__device__ __forceinline__ void stage_ab8(const unsigned char* __restrict__ Ag,
                                          const float* __restrict__ Bg,
                                          char* Ad, char* Bd, int ks, int t)
{
    #pragma unroll
    for (int p = 0; p < 2; ++p) {
        const int idx = p * 256 + t;
        const int row = idx >> 2, pc = idx & 3;
        const int lp = pc ^ (row & 3);
        glds16(Ag + (size_t)row * 256 + ks * 64 + lp * 16, Ad + idx * 16);
        const float* wp = Bg + (size_t)row * NC + ks * 64 + lp * 16;
        const float4 u0 = *(const float4*)wp;
        const float4 u1 = *(const float4*)(wp + 4);
        const float4 u2 = *(const float4*)(wp + 8);
        const float4 u3 = *(const float4*)(wp + 12);
        uint4 pk;
        pk.x = fp8x4(u0.x, u0.y, u0.z, u0.w);
        pk.y = fp8x4(u1.x, u1.y, u1.z, u1.w);
        pk.z = fp8x4(u2.x, u2.y, u2.z, u2.w);
        pk.w = fp8x4(u3.x, u3.y, u3.z, u3.w);
        *(uint4*)(Bd + idx * 16) = pk;
    }
}

__global__ __launch_bounds__(256, 3) void qkv_gemm_kernel(
    const unsigned char* __restrict__ Xt8, const float* __restrict__ w_in,
    const float* __restrict__ b_in, unsigned char* __restrict__ Qt8,
    unsigned char* __restrict__ Kt8, unsigned char* __restrict__ Vf8)
{
    __shared__ char smem[34816];   // loop: A0|A1|B0|B1 8K each; epi: Ls 34.8K
    char* const A0 = smem;
    char* const A1 = smem + 8192;
    char* const B0 = smem + 16384;
    char* const B1 = smem + 24576;

    const int t  = threadIdx.x;
    const int wv = t >> 6, ln = t & 63, lo = ln & 15, hi = ln >> 4;
    const int wm = wv >> 1, wn = wv & 1;
    const int n0 = blockIdx.x * 128, o0 = blockIdx.y * 128, b = blockIdx.z;

    const unsigned char* Ag = Xt8 + ((size_t)b * NN + n0) * 256;
    const float* Bg = w_in + (size_t)o0 * NC;

    f32x4 acc[4][4];
    #pragma unroll
    for (int i = 0; i < 4; ++i)
        #pragma unroll
        for (int j = 0; j < 4; ++j) acc[i][j] = (f32x4){0.f, 0.f, 0.f, 0.f};

    int ra[4], rb[4];
    #pragma unroll
    for (int f = 0; f < 4; ++f) { ra[f] = wm * 64 + f * 16 + lo; rb[f] = wn * 64 + f * 16 + lo; }

    stage_ab8(Ag, Bg, A0, B0, 0, t);
    __syncthreads();
    #pragma unroll
    for (int ks = 0; ks < 4; ++ks) {
        char* Ac = (ks & 1) ? A1 : A0;
        char* Bc = (ks & 1) ? B1 : B0;
        if (ks < 3)
            stage_ab8(Ag, Bg, (ks & 1) ? A0 : A1, (ks & 1) ? B0 : B1, ks + 1, t);
        #pragma unroll
        for (int kk = 0; kk < 2; ++kk) {
            i64 av[4], bv[4];
            #pragma unroll
            for (int f = 0; f < 4; ++f) {
                av[f] = *(const i64*)(Ac + ra[f] * 64 + (((kk << 2) | hi) ^ ((ra[f] & 3) << 1)) * 8);
                bv[f] = *(const i64*)(Bc + rb[f] * 64 + (((kk << 2) | hi) ^ ((rb[f] & 3) << 1)) * 8);
            }
            #pragma unroll
            for (int fm = 0; fm < 4; ++fm)
                #pragma unroll
                for (int fn = 0; fn < 4; ++fn)
                    acc[fm][fn] = __builtin_amdgcn_mfma_f32_16x16x32_fp8_fp8(
                        av[fm], bv[fn], acc[fm][fn], 0, 0, 0);
        }
        __syncthreads();
    }

    float bias[4];
    #pragma unroll
    for (int fn = 0; fn < 4; ++fn) bias[fn] = b_in[o0 + wn * 64 + fn * 16 + lo];

    __hip_bfloat16* Ls = (__hip_bfloat16*)smem;  // [128][136] bf16
    if (o0 < 512) {
        #pragma unroll
        for (int fm = 0; fm < 4; ++fm)
            #pragma unroll
            for (int fn = 0; fn < 4; ++fn)
                #pragma unroll
                for (int r = 0; r < 4; ++r)
                    Ls[(wm * 64 + fm * 16 + hi * 4 + r) * 136 + wn * 64 + fn * 16 + lo] =
                        __float2bfloat16(acc[fm][fn][r] + bias[fn]);
        __syncthreads();
        unsigned char* dst = (o0 < 256) ? Qt8 : Kt8;
        const int oc = (o0 < 256) ? o0 : o0 - 256;
        #pragma unroll
        for (int p = 0; p < 4; ++p) {
            const int idx = p * 256 + t, row = idx >> 3, ch = idx & 7;  // 16-c chunks
            const unsigned* ls = (const unsigned*)&Ls[row * 136 + ch * 16];
            const uint4 a = *(const uint4*)ls;
            const uint4 b2 = *(const uint4*)(ls + 4);
            uint4 o;
            o.x = fp8x4(bflo(a.x), bfhi(a.x), bflo(a.y), bfhi(a.y));
            o.y = fp8x4(bflo(a.z), bfhi(a.z), bflo(a.w), bfhi(a.w));
            o.z = fp8x4(bflo(b2.x), bfhi(b2.x), bflo(b2.y), bfhi(b2.y));
            o.w = fp8x4(bflo(b2.z), bfhi(b2.z), bflo(b2.w), bfhi(b2.w));
            *(uint4*)(dst + ((size_t)b * NN + n0 + row) * 256 + oc + ch * 16) = o;
        }
    } else {
        #pragma unroll
        for (int fm = 0; fm < 4; ++fm)
            #pragma unroll
            for (int fn = 0; fn < 4; ++fn)
                #pragma unroll
                for (int r = 0; r < 4; ++r)
                    Ls[(wn * 64 + fn * 16 + lo) * 136 + wm * 64 + fm * 16 + hi * 4 + r] =
                        __float2bfloat16(acc[fm][fn][r] + bias[fn]);
        __syncthreads();
        // Vf8[b][g][c][8]: 8B per (g, c-row); coalesced over consecutive c
        #pragma unroll
        for (int p = 0; p < 8; ++p) {
            const int idx = p * 256 + t;
            const int ch = idx >> 7, cr = idx & 127;   // ch: 8-key group, cr: c row
            const unsigned* ls = (const unsigned*)&Ls[cr * 136 + ch * 8];
            const uint4 a = *(const uint4*)ls;
            uint2 o;
            o.x = fp8x4(bflo(a.x), bfhi(a.x), bflo(a.y), bfhi(a.y));
            o.y = fp8x4(bflo(a.z), bfhi(a.z), bflo(a.w), bfhi(a.w));
            const int g = (n0 >> 3) + ch;
            *(uint2*)(Vf8 + (((size_t)b * 128 + g) * 256 + (o0 - 512) + cr) * 8) = o;
        }
    }
}

// ---------------------------------------------------------------------------
// Kernel 2: flash attention — fp8 loop (r9, unchanged) + fused out-projection
// epilogue with T14 issue-early W loads (half0 before merge, half1 before
// GEMM0) so global latency hides under merge / GEMM0.
// ---------------------------------------------------------------------------
__device__ __forceinline__ void stage_tile(const unsigned char* __restrict__ Kb,
                                           const unsigned char* __restrict__ Vb,
                                           char* Kd, char* Vd, int m0, int t)
{
    {   // K: 512 x 16B units, 1 per thread
        const int row = t >> 4, pc = t & 15;
        const int prow = (row & 19) | ((row & 4) << 1) | ((row & 8) >> 1); // pi
        const int sc = pc ^ (row & 15);
        glds16(Kb + (size_t)(m0 + prow) * 256 + sc * 16, Kd + t * 16);
    }
    {   // V: pure linear 8KB copy (global layout matches LDS layout)
        glds16(Vb + (size_t)(m0 >> 3) * 2048 + t * 16, Vd + t * 16);
    }
}

__global__ __launch_bounds__(512, 2) void attn_kernel(
    const unsigned char* __restrict__ Qt8, const unsigned char* __restrict__ Kt8,
    const unsigned char* __restrict__ Vf8, const float* __restrict__ w_out,
    const float* __restrict__ b_out, const float* __restrict__ xg,
    float* __restrict__ out)
{
    __shared__ char smem[139264];

    const int t  = threadIdx.x;
    const int wv = t >> 6, ln = t & 63;
    const int l32 = ln & 31, h2 = ln >> 5;
    const int qgrp = wv & 3, half = wv >> 2;
    const int wid = blockIdx.x + 8 * blockIdx.y;
    const int swz = (wid & 7) * 32 + (wid >> 3);       // XCD gets 4 batches
    const int qb = swz & 7, b = swz >> 3;
    const int n0 = qb * 128;
    const float scale = 0.0625f;  // 1/sqrt(256)

    const unsigned char* Kbase = Kt8 + (size_t)b * NN * 256;
    const unsigned char* Vbase = Vf8 + (size_t)b * 128 * 2048;

    const unsigned char* qp = Qt8 + ((size_t)b * NN + n0 + qgrp * 32 + l32) * 256;
    i64 qf[16];
    #pragma unroll
    for (int ks = 0; ks < 16; ++ks)
        qf[ks] = *(const i64*)(qp + ks * 16 + h2 * 8);

    f32x16 acc[8];
    #pragma unroll
    for (int ct = 0; ct < 8; ++ct)
        #pragma unroll
        for (int r = 0; r < 16; ++r) acc[ct][r] = 0.f;
    float mr = 0.f;
    float sr = 0.f;

    #pragma unroll
    for (int tt = 0; tt < 4; ++tt)
        stage_tile(Kbase, Vbase, smem + tt * 8192, smem + 32768 + tt * 8192,
                   tt * 32, t);
    __syncthreads();

    for (int s = 0; s < 16; ++s) {
        if (s < 15) {
            const int t2 = 2 * s + 2, t3 = 2 * s + 3;
            stage_tile(Kbase, Vbase, smem + (t2 & 3) * 8192,
                       smem + 32768 + (t2 & 3) * 8192, t2 * 32, t);
            stage_tile(Kbase, Vbase, smem + (t3 & 3) * 8192,
                       smem + 32768 + (t3 & 3) * 8192, t3 * 32, t);
        }
        const int tile = 2 * s + half;
        char* const Kc = smem + (tile & 3) * 8192;
        char* const Vc = smem + 32768 + (tile & 3) * 8192;

        // S^T = K Q^T : two independent 8-deep chains (fp8, K=16)
        f32x16 sfA, sfB;
        #pragma unroll
        for (int r = 0; r < 16; ++r) { sfA[r] = 0.f; sfB[r] = 0.f; }
        __builtin_amdgcn_s_setprio(1);
        #pragma unroll
        for (int ks = 0; ks < 8; ++ks) {
            const int pc = ks ^ (l32 & 15);
            const i64 kf = *(const i64*)(Kc + l32 * 256 + pc * 16 + h2 * 8);
            sfA = __builtin_amdgcn_mfma_f32_32x32x16_fp8_fp8(kf, qf[ks], sfA, 0, 0, 0);
        }
        #pragma unroll
        for (int ks = 8; ks < 16; ++ks) {
            const int pc = ks ^ (l32 & 15);
            const i64 kf = *(const i64*)(Kc + l32 * 256 + pc * 16 + h2 * 8);
            sfB = __builtin_amdgcn_mfma_f32_32x32x16_fp8_fp8(kf, qf[ks], sfB, 0, 0, 0);
        }
        __builtin_amdgcn_s_setprio(0);

        float sv[16];
        #pragma unroll
        for (int r = 0; r < 16; ++r) sv[r] = sfA[r] + sfB[r];

        float m0a = fmaxf(sv[0], sv[1]),  m1a = fmaxf(sv[2], sv[3]);
        float m2a = fmaxf(sv[4], sv[5]),  m3a = fmaxf(sv[6], sv[7]);
        float m4a = fmaxf(sv[8], sv[9]),  m5a = fmaxf(sv[10], sv[11]);
        float m6a = fmaxf(sv[12], sv[13]), m7a = fmaxf(sv[14], sv[15]);
        float m0b = fmaxf(m0a, m1a), m1b = fmaxf(m2a, m3a);
        float m2b = fmaxf(m4a, m5a), m3b = fmaxf(m6a, m7a);
        float tm = fmaxf(fmaxf(m0b, m1b), fmaxf(m2b, m3b));
        tm = fmaxf(tm, __shfl_xor(tm, 32, 64));
        tm *= scale;
        if (__any(tm > mr + 8.f)) {
            const float mn = fmaxf(mr, tm);
            const float al = __expf(mr - mn);
            mr = mn;
            sr *= al;
            #pragma unroll
            for (int ct = 0; ct < 8; ++ct)
                #pragma unroll
                for (int r = 0; r < 16; ++r) acc[ct][r] *= al;
        }
        float p[16];
        #pragma unroll
        for (int r = 0; r < 16; ++r)
            p[r] = __expf(sv[r] * scale - mr);
        float s0a = p[0] + p[1],  s1a = p[2] + p[3];
        float s2a = p[4] + p[5],  s3a = p[6] + p[7];
        float s4a = p[8] + p[9],  s5a = p[10] + p[11];
        float s6a = p[12] + p[13], s7a = p[14] + p[15];
        float sacc = ((s0a + s1a) + (s2a + s3a)) + ((s4a + s5a) + (s6a + s7a));
        sacc += __shfl_xor(sacc, 32, 64);
        sr += sacc;

        i64 pb[2];
        #pragma unroll
        for (int kstep = 0; kstep < 2; ++kstep) {
            union { unsigned u[2]; i64 l; } uu;
            uu.u[0] = fp8x4(p[8 * kstep + 0], p[8 * kstep + 1],
                            p[8 * kstep + 2], p[8 * kstep + 3]);
            uu.u[1] = fp8x4(p[8 * kstep + 4], p[8 * kstep + 5],
                            p[8 * kstep + 6], p[8 * kstep + 7]);
            pb[kstep] = uu.l;
        }

        __builtin_amdgcn_s_setprio(1);
        #pragma unroll
        for (int ct = 0; ct < 8; ++ct) {
            #pragma unroll
            for (int kstep = 0; kstep < 2; ++kstep) {
                const i64 vf = *(const i64*)(Vc + (2 * kstep + h2) * 2048 +
                                             (ct * 32 + l32) * 8);
                acc[ct] = __builtin_amdgcn_mfma_f32_32x32x16_fp8_fp8(vf, pb[kstep], acc[ct], 0, 0, 0);
            }
        }
        __builtin_amdgcn_s_setprio(0);
        __syncthreads();
    }

    // ---- T14: issue W half-0 global loads NOW (hide under pair-merge) ----
    const int wo = t >> 5, wck = t & 31;   // unit: o-row (per 512 thr: 16 rows/iter)
    float4 wr[16];
    #pragma unroll
    for (int p = 0; p < 8; ++p) {
        const int o = p * 16 + wo;
        const float* wp = w_out + (size_t)o * NC + wck * 8;
        wr[2 * p]     = *(const float4*)wp;
        wr[2 * p + 1] = *(const float4*)(wp + 4);
    }

    // ---- pair merge (2 phases) -> H bf16 in LDS ----
    float* const ex = (float*)smem;                              // 128 x 132 f32
    __hip_bfloat16* const Hld = (__hip_bfloat16*)(smem + 69632); // [128][264]
    #pragma unroll
    for (int ph = 0; ph < 2; ++ph) {
        if (half == 1 && (qgrp >> 1) == ph) {
            float* dst = ex + ((qgrp & 1) * 64 + ln) * 132;
            #pragma unroll
            for (int ct = 0; ct < 8; ++ct)
                #pragma unroll
                for (int rr = 0; rr < 4; ++rr) {
                    f32x4 v = {acc[ct][rr * 4 + 0], acc[ct][rr * 4 + 1],
                               acc[ct][rr * 4 + 2], acc[ct][rr * 4 + 3]};
                    *(f32x4*)(dst + ct * 16 + rr * 4) = v;
                }
            dst[128] = mr;
            dst[129] = sr;
        }
        __syncthreads();
        if (half == 0 && (qgrp >> 1) == ph) {
            const float* src = ex + ((qgrp & 1) * 64 + ln) * 132;
            const float mb = src[128], lb = src[129];
            const float m = fmaxf(mr, mb);
            float fa = __expf(mr - m), fb = __expf(mb - m);
            const float inv = 1.0f / (sr * fa + lb * fb);
            fa *= inv; fb *= inv;
            __hip_bfloat16* hrow = Hld + (size_t)(qgrp * 32 + l32) * 264;
            #pragma unroll
            for (int ct = 0; ct < 8; ++ct)
                #pragma unroll
                for (int ss = 0; ss < 4; ++ss) {
                    const float o0 = acc[ct][ss * 4 + 0] * fa + src[ct * 16 + ss * 4 + 0] * fb;
                    const float o1 = acc[ct][ss * 4 + 1] * fa + src[ct * 16 + ss * 4 + 1] * fb;
                    const float o2 = acc[ct][ss * 4 + 2] * fa + src[ct * 16 + ss * 4 + 2] * fb;
                    const float o3 = acc[ct][ss * 4 + 3] * fa + src[ct * 16 + ss * 4 + 3] * fb;
                    uint2 v;
                    v.x = pack2(o0, o1);
                    v.y = pack2(o2, o3);
                    *(uint2*)(hrow + ct * 32 + ss * 8 + h2 * 4) = v;
                }
        }
        __syncthreads();
    }

    // ---- fused output projection: out = W_out * H^T + b_out + x ----
    __hip_bfloat16* const Wld = (__hip_bfloat16*)smem;   // [128][264], over ex
    const int oT = wv >> 1;
    const int nT0 = (wv & 1) * 2, nT1 = nT0 + 1;

    // write W half-0 from regs (merge done; ex area dead)
    #pragma unroll
    for (int p = 0; p < 8; ++p) {
        const int o = p * 16 + wo;
        uint4 pk;
        pk.x = pack2(wr[2*p].x, wr[2*p].y);     pk.y = pack2(wr[2*p].z, wr[2*p].w);
        pk.z = pack2(wr[2*p+1].x, wr[2*p+1].y); pk.w = pack2(wr[2*p+1].z, wr[2*p+1].w);
        *(uint4*)((char*)Wld + (size_t)o * 528 + wck * 16) = pk;
    }
    // issue W half-1 loads (overlap GEMM0 + store0)
    #pragma unroll
    for (int p = 0; p < 8; ++p) {
        const int o = 128 + p * 16 + wo;
        const float* wp = w_out + (size_t)o * NC + wck * 8;
        wr[2 * p]     = *(const float4*)wp;
        wr[2 * p + 1] = *(const float4*)(wp + 4);
    }
    __syncthreads();

    #pragma unroll
    for (int oh = 0; oh < 2; ++oh) {
        f32x16 oc0, oc1;
        #pragma unroll
        for (int r = 0; r < 16; ++r) { oc0[r] = 0.f; oc1[r] = 0.f; }
        __builtin_amdgcn_s_setprio(1);
        #pragma unroll
        for (int ks = 0; ks < 16; ++ks) {
            const int ck = ks * 2 + h2;
            bf16x8 wf = *(const bf16x8*)((char*)Wld + (size_t)(oT * 32 + l32) * 528 + ck * 16);
            bf16x8 hf0 = *(const bf16x8*)((char*)Hld + (size_t)(nT0 * 32 + l32) * 528 + ck * 16);
            bf16x8 hf1 = *(const bf16x8*)((char*)Hld + (size_t)(nT1 * 32 + l32) * 528 + ck * 16);
            oc0 = __builtin_amdgcn_mfma_f32_32x32x16_bf16(wf, hf0, oc0, 0, 0, 0);
            oc1 = __builtin_amdgcn_mfma_f32_32x32x16_bf16(wf, hf1, oc1, 0, 0, 0);
        }
        __builtin_amdgcn_s_setprio(0);

        #pragma unroll
        for (int r = 0; r < 16; ++r) {
            const int o = oh * 128 + oT * 32 + (r & 3) + 8 * (r >> 2) + 4 * h2;
            const float bo = b_out[o];
            const size_t rowg = ((size_t)b * NC + o) * NN + n0;
            const size_t g0 = rowg + nT0 * 32 + l32;
            const size_t g1 = rowg + nT1 * 32 + l32;
            out[g0] = oc0[r] + bo + xg[g0];
            out[g1] = oc1[r] + bo + xg[g1];
        }
        __syncthreads();   // Wld reads done before overwrite
        if (oh == 0) {
            // write W half-1 from regs
            #pragma unroll
            for (int p = 0; p < 8; ++p) {
                const int o = p * 16 + wo;
                uint4 pk;
                pk.x = pack2(wr[2*p].x, wr[2*p].y);     pk.y = pack2(wr[2*p].z, wr[2*p].w);
                pk.z = pack2(wr[2*p+1].x, wr[2*p+1].y); pk.w = pack2(wr[2*p+1].z, wr[2*p+1].w);
                *(uint4*)((char*)Wld + (size_t)o * 528 + wck * 16) = pk;
            }
            __syncthreads();
        }
    }
}

// ---------------------------------------------------------------------------
extern "C" void kernel_launch(void* const* d_in, const int* in_sizes, int n_in,
                              void* d_out, int out_size, void* d_ws, size_t ws_size,
                              hipStream_t stream) {
    const float* x     = (const float*)d_in[0];
    const float* w_in  = (const float*)d_in[1];
    const float* b_in  = (const float*)d_in[2];
    const float* w_out = (const float*)d_in[3];
    const float* b_out = (const float*)d_in[4];
    float* out = (float*)d_out;

    if (ws_size < (size_t)64 * 1024 * 1024) return;  // fail loud
    char* ws = (char*)d_ws;
    unsigned char* Qt8 = (unsigned char*)(ws);                       // 8 MB
    unsigned char* Kt8 = (unsigned char*)(ws + ((size_t)8 << 20));   // 8 MB
    unsigned char* Vf8 = (unsigned char*)(ws + ((size_t)16 << 20));  // 8 MB
    unsigned char* Xt8 = (unsigned char*)(ws + ((size_t)24 << 20));  // 8 MB

    xpose_kernel<<<dim3(16, 4, 32), 256, 0, stream>>>(x, Xt8);
    qkv_gemm_kernel<<<dim3(8, 6, 32), 256, 0, stream>>>(Xt8, w_in, b_in, Qt8, Kt8, Vf8);
    attn_kernel<<<dim3(8, 32), 512, 0, stream>>>(Qt8, Kt8, Vf8, w_out, b_out, x, out);
}